// Round 18
// baseline (344.974 us; speedup 1.0000x reference)
//
#include <hip/hip_runtime.h>
#include <hip/hip_bf16.h>

#define NB 4
#define NT 2048
#define ND 1024
#define NH 16
#define NHD 64
#define NF 4096
#define MTOK (NB*NT)  // 8192

typedef float f32x4 __attribute__((ext_vector_type(4)));
typedef __bf16 bf16x8 __attribute__((ext_vector_type(8)));
typedef short s16x8 __attribute__((ext_vector_type(8)));
typedef unsigned short ushort_t;

__device__ inline ushort_t f2bf(float f) {
    unsigned int u = __builtin_bit_cast(unsigned int, f);
    unsigned int r = (u + 0x7FFFu + ((u >> 16) & 1u)) >> 16;
    return (ushort_t)r;
}
__device__ inline float bf2f(ushort_t u) {
    return __builtin_bit_cast(float, (unsigned int)u << 16);
}

__device__ __forceinline__ void async_load16(const void* g, void* l) {
    __builtin_amdgcn_global_load_lds(
        (const __attribute__((address_space(1))) void*)g,
        (__attribute__((address_space(3))) void*)l, 16, 0, 0);
}

__device__ __forceinline__ unsigned int cvt_pk_bf16(float lo, float hi) {
    unsigned int r;
    asm("v_cvt_pk_bf16_f32 %0, %1, %2" : "=v"(r) : "v"(lo), "v"(hi));
    return r;
}

__device__ __forceinline__ float exp2_fast(float x) {
    float r;
    asm("v_exp_f32 %0, %1" : "=v"(r) : "v"(x));
    return r;
}

// ---------------------------------------------------------------------------
// Transpose-convert: src fp32 (R x C) row-major -> dst bf16 (C x R) row-major
// ---------------------------------------------------------------------------
__global__ __launch_bounds__(256)
void transpose_to_bf16(const float* __restrict__ src, ushort_t* __restrict__ dst,
                       int R, int C) {
    __shared__ float tile[32][33];
    int c0 = blockIdx.x * 32, r0 = blockIdx.y * 32;
    #pragma unroll
    for (int i = 0; i < 32; i += 8)
        tile[threadIdx.y + i][threadIdx.x] =
            src[(size_t)(r0 + threadIdx.y + i) * C + c0 + threadIdx.x];
    __syncthreads();
    #pragma unroll
    for (int i = 0; i < 32; i += 8)
        dst[(size_t)(c0 + threadIdx.y + i) * R + r0 + threadIdx.x] =
            f2bf(tile[threadIdx.x][threadIdx.y + i]);
}

// QKV weights: Wq/Wk/Wv are (H, D, HD). Build Bt (3072 x 1024) bf16.
// Wq pre-scaled by (1/32)*log2(e): QK^T scores come out in exp2 domain.
__global__ __launch_bounds__(256)
void transpose_qkv_to_bf16(const float* __restrict__ Wq, const float* __restrict__ Wk,
                           const float* __restrict__ Wv, ushort_t* __restrict__ dst) {
    __shared__ float tile[32][33];
    int z = blockIdx.z;            // 0..47
    int w = z >> 4, h = z & 15;
    const float* src = (w == 0 ? Wq : (w == 1 ? Wk : Wv)) + (size_t)h * ND * NHD;
    const float sc = (w == 0) ? 0.03125f * 1.44269504f : 1.0f;
    ushort_t* out = dst + ((size_t)w * ND + h * NHD) * ND;
    int c0 = blockIdx.x * 32, r0 = blockIdx.y * 32;
    #pragma unroll
    for (int i = 0; i < 32; i += 8)
        tile[threadIdx.y + i][threadIdx.x] =
            src[(size_t)(r0 + threadIdx.y + i) * NHD + c0 + threadIdx.x];
    __syncthreads();
    #pragma unroll
    for (int i = 0; i < 32; i += 8)
        out[(size_t)(c0 + threadIdx.y + i) * ND + r0 + threadIdx.x] =
            f2bf(tile[threadIdx.x][threadIdx.y + i] * sc);
}

// ---------------------------------------------------------------------------
// LayerNorm (rows of 1024 fp32) -> bf16 out
// ---------------------------------------------------------------------------
__global__ __launch_bounds__(256)
void layernorm_to_bf16(const float* __restrict__ x, const float* __restrict__ g,
                       const float* __restrict__ bvec, ushort_t* __restrict__ out) {
    int row = blockIdx.x;
    const float4* xr = (const float4*)(x + (size_t)row * ND);
    float4 v = xr[threadIdx.x];
    float s = v.x + v.y + v.z + v.w;
    float s2 = v.x * v.x + v.y * v.y + v.z * v.z + v.w * v.w;
    #pragma unroll
    for (int o = 32; o >= 1; o >>= 1) {
        s += __shfl_xor(s, o);
        s2 += __shfl_xor(s2, o);
    }
    __shared__ float red[8];
    int wave = threadIdx.x >> 6, lane = threadIdx.x & 63;
    if (lane == 0) { red[wave] = s; red[4 + wave] = s2; }
    __syncthreads();
    float ts = red[0] + red[1] + red[2] + red[3];
    float ts2 = red[4] + red[5] + red[6] + red[7];
    float mu = ts * (1.f / ND);
    float var = ts2 * (1.f / ND) - mu * mu;
    float rs = rsqrtf(var + 1e-5f);
    float4 gv = ((const float4*)g)[threadIdx.x];
    float4 bv = ((const float4*)bvec)[threadIdx.x];
    ushort4 o4;
    o4.x = f2bf((v.x - mu) * rs * gv.x + bv.x);
    o4.y = f2bf((v.y - mu) * rs * gv.y + bv.y);
    o4.z = f2bf((v.z - mu) * rs * gv.z + bv.z);
    o4.w = f2bf((v.w - mu) * rs * gv.w + bv.w);
    ((ushort4*)(out + (size_t)row * ND))[threadIdx.x] = o4;
}

// LayerNorm on bf16 input (rows of 1024) -> bf16 out
__global__ __launch_bounds__(256)
void layernorm_bf16(const ushort_t* __restrict__ x, const float* __restrict__ g,
                    const float* __restrict__ bvec, ushort_t* __restrict__ out) {
    int row = blockIdx.x;
    ushort4 u4 = ((const ushort4*)(x + (size_t)row * ND))[threadIdx.x];
    float4 v;
    v.x = bf2f(u4.x); v.y = bf2f(u4.y); v.z = bf2f(u4.z); v.w = bf2f(u4.w);
    float s = v.x + v.y + v.z + v.w;
    float s2 = v.x * v.x + v.y * v.y + v.z * v.z + v.w * v.w;
    #pragma unroll
    for (int o = 32; o >= 1; o >>= 1) {
        s += __shfl_xor(s, o);
        s2 += __shfl_xor(s2, o);
    }
    __shared__ float red[8];
    int wave = threadIdx.x >> 6, lane = threadIdx.x & 63;
    if (lane == 0) { red[wave] = s; red[4 + wave] = s2; }
    __syncthreads();
    float ts = red[0] + red[1] + red[2] + red[3];
    float ts2 = red[4] + red[5] + red[6] + red[7];
    float mu = ts * (1.f / ND);
    float var = ts2 * (1.f / ND) - mu * mu;
    float rs = rsqrtf(var + 1e-5f);
    float4 gv = ((const float4*)g)[threadIdx.x];
    float4 bv = ((const float4*)bvec)[threadIdx.x];
    ushort4 o4;
    o4.x = f2bf((v.x - mu) * rs * gv.x + bv.x);
    o4.y = f2bf((v.y - mu) * rs * gv.y + bv.y);
    o4.z = f2bf((v.z - mu) * rs * gv.z + bv.z);
    o4.w = f2bf((v.w - mu) * rs * gv.w + bv.w);
    ((ushort4*)(out + (size_t)row * ND))[threadIdx.x] = o4;
}

// ---------------------------------------------------------------------------
// gemm8p: 256x256 tile, BK=64, 4 phases/tile, counted vmcnt(6) at q3.
// (FFN1 path — verified.)
// ---------------------------------------------------------------------------
template<bool HAS_BIAS, bool RELU, int RES_MODE, bool OUT_F32>
__global__ __launch_bounds__(512, 2)
void gemm8p(const ushort_t* __restrict__ A, const ushort_t* __restrict__ Bt,
            const float* __restrict__ bias, const void* __restrict__ res,
            void* __restrict__ outp, int M, int N, int K) {
    constexpr int BN = 256;
    constexpr int NFR = BN / 64;
    __shared__ __align__(16) ushort_t As[2][256 * 64];
    __shared__ __align__(16) ushort_t Bs[2][BN * 64];
    const int t = threadIdx.x;
    const int wave = t >> 6, lane = t & 63;
    const int wm = wave >> 2, wn = wave & 3;
    const int g = lane >> 4, l16 = lane & 15;
    int wid = blockIdx.y * gridDim.x + blockIdx.x;
    const int cpx = (gridDim.x * gridDim.y) >> 3;
    wid = (wid & 7) * cpx + (wid >> 3);
    const int m0 = (wid / gridDim.x) * 256;
    const int n0 = (wid % gridDim.x) * BN;
    const int lrow8 = lane >> 3;
    const int srcCol = ((lane & 7) ^ lrow8) * 8;
    const ushort_t* Abase = A + (size_t)m0 * K + srcCol;
    const ushort_t* Bbase = Bt + (size_t)n0 * K + srcCol;
    const int NKT = K >> 6;

    f32x4 acc[8][NFR] = {};

    auto stageAhalf = [&](int kt, int h, int slot) {
        #pragma unroll
        for (int j = 2 * h; j < 2 * h + 2; j++) {
            const int rowbase = j * 64 + wave * 8;
            async_load16(Abase + (size_t)(rowbase + lrow8) * K + kt * 64,
                         &As[slot][rowbase * 64]);
        }
    };
    auto stageBhalf = [&](int kt, int h, int slot) {
        #pragma unroll
        for (int j = 2 * h; j < 2 * h + 2; j++) {
            const int rowbase = j * 64 + wave * 8;
            async_load16(Bbase + (size_t)(rowbase + lrow8) * K + kt * 64,
                         &Bs[slot][rowbase * 64]);
        }
    };

    stageAhalf(0, 0, 0); stageAhalf(0, 1, 0);
    stageBhalf(0, 0, 0); stageBhalf(0, 1, 0);
    stageBhalf(1, 0, 1); stageBhalf(1, 1, 1);
    stageAhalf(1, 0, 1);
    asm volatile("s_waitcnt vmcnt(6)" ::: "memory");
    __builtin_amdgcn_s_barrier();
    __builtin_amdgcn_sched_barrier(0);

    for (int kt = 0; kt < NKT; ++kt) {
        const int cur = kt & 1, nxt = cur ^ 1;
        const ushort_t* as = As[cur];
        const ushort_t* bs = Bs[cur];
        bf16x8 bfr[NFR][2];
        #pragma unroll
        for (int q = 0; q < 4; q++) {
            if (q == 0) {
                #pragma unroll
                for (int nf = 0; nf < NFR; nf++)
                    #pragma unroll
                    for (int ks = 0; ks < 2; ks++) {
                        const int row = wn * (BN / 4) + nf * 16 + l16;
                        int a = row * 128 + ks * 64 + 16 * g;
                        a ^= (row & 7) << 4;
                        bfr[nf][ks] = *(const bf16x8*)((const char*)bs + a);
                    }
            }
            bf16x8 af[2][2];
            #pragma unroll
            for (int mi2 = 0; mi2 < 2; mi2++)
                #pragma unroll
                for (int ks = 0; ks < 2; ks++) {
                    const int row = q * 64 + wm * 32 + mi2 * 16 + l16;
                    int a = row * 128 + ks * 64 + 16 * g;
                    a ^= (row & 7) << 4;
                    af[mi2][ks] = *(const bf16x8*)((const char*)as + a);
                }
            if (q == 0)      { if (kt + 1 < NKT) stageAhalf(kt + 1, 1, nxt); }
            else if (q == 1) { if (kt + 2 < NKT) stageBhalf(kt + 2, 0, cur); }
            else if (q == 2) { if (kt + 2 < NKT) stageBhalf(kt + 2, 1, cur); }
            else             { if (kt + 2 < NKT) stageAhalf(kt + 2, 0, cur); }
            __builtin_amdgcn_sched_barrier(0);
            if (q == 3) {
                if (kt >= NKT - 2) asm volatile("s_waitcnt vmcnt(0)" ::: "memory");
                else               asm volatile("s_waitcnt vmcnt(6)" ::: "memory");
            }
            __builtin_amdgcn_s_barrier();
            __builtin_amdgcn_sched_barrier(0);
            __builtin_amdgcn_s_setprio(1);
            #pragma unroll
            for (int mi2 = 0; mi2 < 2; mi2++)
                #pragma unroll
                for (int nf = 0; nf < NFR; nf++)
                    #pragma unroll
                    for (int ks = 0; ks < 2; ks++)
                        acc[q * 2 + mi2][nf] = __builtin_amdgcn_mfma_f32_16x16x32_bf16(
                            af[mi2][ks], bfr[nf][ks], acc[q * 2 + mi2][nf], 0, 0, 0);
            __builtin_amdgcn_s_setprio(0);
            __builtin_amdgcn_s_barrier();
            __builtin_amdgcn_sched_barrier(0);
        }
    }

    const int gc0 = n0 + wn * (BN / 4) + l16;
    #pragma unroll
    for (int mi = 0; mi < 8; mi++) {
        const int rowb = m0 + (mi >> 1) * 64 + wm * 32 + (mi & 1) * 16 + g * 4;
        #pragma unroll
        for (int nf = 0; nf < NFR; nf++) {
            const int col = gc0 + nf * 16;
            float bb = 0.f;
            if constexpr (HAS_BIAS) bb = bias[col];
            #pragma unroll
            for (int r = 0; r < 4; r++) {
                const int row = rowb + r;
                float v = acc[mi][nf][r] + bb;
                if constexpr (RELU) v = fmaxf(v, 0.f);
                if constexpr (RES_MODE == 1)
                    v += ((const float*)res)[(size_t)row * N + col];
                else if constexpr (RES_MODE == 2)
                    v += bf2f(((const ushort_t*)res)[(size_t)row * N + col]);
                if constexpr (OUT_F32)
                    ((float*)outp)[(size_t)row * N + col] = v;
                else
                    ((ushort_t*)outp)[(size_t)row * N + col] = f2bf(v);
            }
        }
    }
}

// ---------------------------------------------------------------------------
// gemm2b64: 128x128 tile, BK=64, 2 blocks/CU cross-block overlap (round-15
// verified). Counted vmcnt(8); (row&7)<<4 swizzle; 0 conflicts.
// OUT_MODE: 0 normal; 1 qkv-split (n0>=2048 -> V transposed into vTp).
// ---------------------------------------------------------------------------
template<bool HAS_BIAS, bool RELU, int RES_MODE, bool OUT_F32, int OUT_MODE = 0>
__global__ __launch_bounds__(256, 2)
void gemm2b64(const ushort_t* __restrict__ A, const ushort_t* __restrict__ Bt,
              const float* __restrict__ bias, const void* __restrict__ res,
              void* __restrict__ outp, ushort_t* __restrict__ vTp,
              int M, int N, int K) {
    __shared__ __align__(16) ushort_t As[2][128 * 64];
    __shared__ __align__(16) ushort_t Bs[2][128 * 64];
    const int t = threadIdx.x;
    const int wave = t >> 6, lane = t & 63;
    const int wm = wave >> 1, wn = wave & 1;        // 2M x 2N
    const int g = lane >> 4, l16 = lane & 15;
    int wid = blockIdx.y * gridDim.x + blockIdx.x;
    const int cpx = (gridDim.x * gridDim.y) >> 3;
    wid = (wid & 7) * cpx + (wid >> 3);
    const int m0 = (wid / gridDim.x) * 128;
    const int n0 = (wid % gridDim.x) * 128;
    const int rw = lane >> 3, ck = lane & 7;        // 8 rows x 8 chunks of 16B
    const int srcCol = (ck ^ rw) * 8;               // pre-swizzled source (ushorts)
    const ushort_t* Abase = A + (size_t)m0 * K + srcCol;
    const ushort_t* Bbase = Bt + (size_t)n0 * K + srcCol;
    const int NKT = K >> 6;

    f32x4 acc[4][4] = {};   // [mi][nf]

    auto stage = [&](int kt, int slot) {
        #pragma unroll
        for (int j = 0; j < 4; j++) {
            const int rowbase = j * 32 + wave * 8;  // wave-uniform
            async_load16(Abase + (size_t)(rowbase + rw) * K + kt * 64,
                         &As[slot][rowbase * 64]);
        }
        #pragma unroll
        for (int j = 0; j < 4; j++) {
            const int rowbase = j * 32 + wave * 8;
            async_load16(Bbase + (size_t)(rowbase + rw) * K + kt * 64,
                         &Bs[slot][rowbase * 64]);
        }
    };

    stage(0, 0);
    stage(1, 1);

    for (int kt = 0; kt < NKT; ++kt) {
        const int cur = kt & 1;
        if (kt >= NKT - 1) asm volatile("s_waitcnt vmcnt(0)" ::: "memory");
        else               asm volatile("s_waitcnt vmcnt(8)" ::: "memory");
        __builtin_amdgcn_s_barrier();
        __builtin_amdgcn_sched_barrier(0);

        const ushort_t* as = As[cur];
        const ushort_t* bs = Bs[cur];
        bf16x8 af[4][2], bfr[4][2];
        #pragma unroll
        for (int mi = 0; mi < 4; mi++)
            #pragma unroll
            for (int ks = 0; ks < 2; ks++) {
                const int row = wm * 64 + mi * 16 + l16;
                int a = row * 128 + ks * 64 + 16 * g;
                a ^= (row & 7) << 4;
                af[mi][ks] = *(const bf16x8*)((const char*)as + a);
            }
        #pragma unroll
        for (int nf = 0; nf < 4; nf++)
            #pragma unroll
            for (int ks = 0; ks < 2; ks++) {
                const int row = wn * 64 + nf * 16 + l16;
                int a = row * 128 + ks * 64 + 16 * g;
                a ^= (row & 7) << 4;
                bfr[nf][ks] = *(const bf16x8*)((const char*)bs + a);
            }
        __builtin_amdgcn_s_setprio(1);
        #pragma unroll
        for (int mi = 0; mi < 4; mi++)
            #pragma unroll
            for (int nf = 0; nf < 4; nf++)
                #pragma unroll
                for (int ks = 0; ks < 2; ks++)
                    acc[mi][nf] = __builtin_amdgcn_mfma_f32_16x16x32_bf16(
                        af[mi][ks], bfr[nf][ks], acc[mi][nf], 0, 0, 0);
        __builtin_amdgcn_s_setprio(0);
        __builtin_amdgcn_s_barrier();
        __builtin_amdgcn_sched_barrier(0);
        if (kt + 2 < NKT) stage(kt + 2, cur);
    }

    const int gc0 = n0 + wn * 64 + l16;
    if constexpr (OUT_MODE == 1) {
        if (n0 >= 2048) {
            // V -> transposed store: vT[b*1024 + (col-2048)][t], 4 t's per store
            #pragma unroll
            for (int mi = 0; mi < 4; mi++) {
                const int rowb = m0 + wm * 64 + mi * 16 + g * 4;
                const int b = rowb >> 11, tt = rowb & 2047;
                #pragma unroll
                for (int nf = 0; nf < 4; nf++) {
                    const int col = gc0 + nf * 16;
                    ushort4 o4;
                    o4.x = f2bf(acc[mi][nf][0]);
                    o4.y = f2bf(acc[mi][nf][1]);
                    o4.z = f2bf(acc[mi][nf][2]);
                    o4.w = f2bf(acc[mi][nf][3]);
                    *(ushort4*)(vTp + (size_t)(b * 1024 + col - 2048) * NT + tt) = o4;
                }
            }
            return;
        }
    }
    #pragma unroll
    for (int mi = 0; mi < 4; mi++) {
        const int rowb = m0 + wm * 64 + mi * 16 + g * 4;
        #pragma unroll
        for (int nf = 0; nf < 4; nf++) {
            const int col = gc0 + nf * 16;
            float bb = 0.f;
            if constexpr (HAS_BIAS) bb = bias[col];
            #pragma unroll
            for (int r = 0; r < 4; r++) {
                const int row = rowb + r;
                float v = acc[mi][nf][r] + bb;
                if constexpr (RELU) v = fmaxf(v, 0.f);
                if constexpr (RES_MODE == 1)
                    v += ((const float*)res)[(size_t)row * N + col];
                else if constexpr (RES_MODE == 2)
                    v += bf2f(((const ushort_t*)res)[(size_t)row * N + col]);
                if constexpr (OUT_F32)
                    ((float*)outp)[(size_t)row * N + col] = v;
                else
                    ((ushort_t*)outp)[(size_t)row * N + col] = f2bf(v);
            }
        }
    }
}

// ---------------------------------------------------------------------------
// Causal flash attention, no max-tracking; row-sum via ones-MFMA. V arrives
// pre-transposed (vT, written by the QKV GEMM) and is staged like K via
// global_load_lds (source pre-swizzled by c(d)=(d&7)^(d>>3)). P round-trip
// through Pw is VECTORIZED: 36-word row stride (144B = 16B-aligned rows) ->
// 8 ds_write_b64 + 4 ds_read_b128 per wave-iter (was 32 scalar b32 ops).
// QBLK=128: 4 waves x 32 q-rows. Grid (8,64)=512 = 2 blocks/CU.
// ---------------------------------------------------------------------------
__global__ __launch_bounds__(256)
void attn_kernel(const ushort_t* __restrict__ qkv, const ushort_t* __restrict__ vT,
                 ushort_t* __restrict__ out) {
    __shared__ __align__(16) ushort_t Ks[2][64 * 64];  // linear, XOR-swizzle on read
    __shared__ __align__(16) ushort_t Vt[2][64 * 64];  // d-major, XOR-swizzled
    __shared__ __align__(16) unsigned int Pw[4][32][36];  // per-wave P words
    const int L = blockIdx.y * gridDim.x + blockIdx.x; // grid (8,64) -> 512
    const int xcd = L & 7, kk = L >> 3;
    const int bh = ((kk & 7) << 3) | xcd;              // 8 pair-blocks of bh -> one XCD
    const int pairIdx = kk >> 3;                       // 0..7
    const int b = bh >> 4, h = bh & 15;
    const int t = threadIdx.x, wave = t >> 6, lane = t & 63;
    const int g = lane >> 4, q16 = lane & 15;
    const size_t base = ((size_t)b * NT) * 3072 + h * NHD;
    const ushort_t* qp_base = qkv + base;
    const ushort_t* kb = qkv + base + 1024;
    const ushort_t* vbt = vT + (size_t)bh * 64 * NT;   // rows d, length NT
    const int krw = lane >> 3, kck = lane & 7;
    const int ksrc = (kck ^ krw) * 8;                  // pre-swizzled source column

    bf16x8 ones_f;
    {
        uint4 u = {0x3F803F80u, 0x3F803F80u, 0x3F803F80u, 0x3F803F80u};
        ones_f = __builtin_bit_cast(bf16x8, u);
    }

    auto stageK = [&](int kv, int buf) {
        #pragma unroll
        for (int c = 0; c < 2; c++) {
            const int rowbase = c * 32 + wave * 8;     // wave-uniform
            async_load16(kb + (size_t)(kv * 64 + rowbase + krw) * 3072 + ksrc,
                         &Ks[buf][rowbase * 64]);
        }
    };
    auto stageV = [&](int kv, int buf) {
        #pragma unroll
        for (int c = 0; c < 2; c++) {
            const int rowbase = c * 32 + wave * 8;     // wave-uniform
            const int scol = ((kck ^ krw ^ ((c * 4 + wave) & 7)) * 8);
            async_load16(vbt + (size_t)(rowbase + krw) * NT + kv * 64 + scol,
                         &Vt[buf][rowbase * 64]);
        }
    };

    for (int half = 0; half < 2; half++) {
        const int qt = half ? (15 - pairIdx) : pairIdx;
        const int q0 = qt * 128;
        const int wq0 = q0 + wave * 32;
        bf16x8 qf[2][2];
        #pragma unroll
        for (int qb2 = 0; qb2 < 2; qb2++) {
            const ushort_t* qp = qp_base + (size_t)(wq0 + 16 * qb2 + q16) * 3072 + 8 * g;
            qf[qb2][0] = *(const bf16x8*)qp;
            qf[qb2][1] = *(const bf16x8*)(qp + 32);
        }
        f32x4 of[2][4] = {};
        f32x4 of4[2] = {};               // row-sum accumulator (l), via ones-MFMA
        const int nkv = 2 * qt + 2;

        stageK(0, 0);
        stageV(0, 0);
        __syncthreads();                 // drains vmcnt before first use

        for (int kv = 0; kv < nkv; ++kv) {
            const int cur = kv & 1, nxt = cur ^ 1;
            if (kv + 1 < nkv) {
                stageK(kv + 1, nxt);
                stageV(kv + 1, nxt);
            }
            __builtin_amdgcn_sched_barrier(0);   // pin prefetch issue before compute

            const int kbase = kv * 64;
            if (kbase <= wq0 + 31) {
                bf16x8 kf[4][2];
                #pragma unroll
                for (int n = 0; n < 4; n++)
                    #pragma unroll
                    for (int kd = 0; kd < 2; kd++) {
                        int row = n * 16 + q16;
                        int a = row * 128 + (kd * 64 + 16 * g);
                        a ^= ((row & 7) << 4);
                        kf[n][kd] = *(const bf16x8*)((const char*)&Ks[cur][0] + a);
                    }

                f32x4 sf[2][4] = {};
                #pragma unroll
                for (int n = 0; n < 4; n++)
                    #pragma unroll
                    for (int kd = 0; kd < 2; kd++) {
                        sf[0][n] = __builtin_amdgcn_mfma_f32_16x16x32_bf16(
                            kf[n][kd], qf[0][kd], sf[0][n], 0, 0, 0);
                        sf[1][n] = __builtin_amdgcn_mfma_f32_16x16x32_bf16(
                            kf[n][kd], qf[1][kd], sf[1][n], 0, 0, 0);
                    }

                #pragma unroll
                for (int qb2 = 0; qb2 < 2; qb2++) {
                    const int wqb = wq0 + 16 * qb2 + q16;
                    const bool partial = (kbase + 63 > wq0 + 16 * qb2);
                    float p[4][4];
                    #pragma unroll
                    for (int n = 0; n < 4; n++)
                        #pragma unroll
                        for (int r = 0; r < 4; r++) {
                            float v = sf[qb2][n][r];
                            if (partial) {
                                int kg = kbase + n * 16 + 4 * g + r;
                                if (kg > wqb) v = -1.0e30f;   // exp2 -> 0
                            }
                            p[n][r] = exp2_fast(v);
                        }
                    unsigned int* pr = &Pw[wave][16 * qb2 + q16][0];
                    #pragma unroll
                    for (int n = 0; n < 4; n++) {
                        uint2 wv;
                        wv.x = cvt_pk_bf16(p[n][0], p[n][1]);
                        wv.y = cvt_pk_bf16(p[n][2], p[n][3]);
                        *(uint2*)(pr + 8 * n + 2 * g) = wv;   // 8B-aligned
                    }
                }

                #pragma unroll
                for (int kbk = 0; kbk < 2; kbk++) {
                    bf16x8 pfr[2];
                    #pragma unroll
                    for (int qb2 = 0; qb2 < 2; qb2++) {
                        const unsigned int* pr = &Pw[wave][16 * qb2 + q16][0];
                        uint4 pu = *(const uint4*)(pr + 16 * kbk + 4 * g);  // 16B-aligned
                        pfr[qb2] = __builtin_bit_cast(bf16x8, pu);
                    }
                    of4[0] = __builtin_amdgcn_mfma_f32_16x16x32_bf16(
                        ones_f, pfr[0], of4[0], 0, 0, 0);
                    of4[1] = __builtin_amdgcn_mfma_f32_16x16x32_bf16(
                        ones_f, pfr[1], of4[1], 0, 0, 0);
                    #pragma unroll
                    for (int nf = 0; nf < 4; nf++) {
                        const int d = nf * 16 + q16;
                        int a = (d << 7) + (kbk * 64 + 16 * g);
                        a ^= (((d & 7) ^ ((d >> 3) & 7)) << 4);
                        bf16x8 vf = *(const bf16x8*)((const char*)&Vt[cur][0] + a);
                        of[0][nf] = __builtin_amdgcn_mfma_f32_16x16x32_bf16(
                            vf, pfr[0], of[0][nf], 0, 0, 0);
                        of[1][nf] = __builtin_amdgcn_mfma_f32_16x16x32_bf16(
                            vf, pfr[1], of[1][nf], 0, 0, 0);
                    }
                }
            }

            __syncthreads();   // drains K+V prefetch + buffer handoff
        }

        #pragma unroll
        for (int qb2 = 0; qb2 < 2; qb2++) {
            float rl = 1.f / of4[qb2][0];
            const size_t orow = (size_t)b * NT + q0 + wave * 32 + 16 * qb2 + q16;
            #pragma unroll
            for (int nf = 0; nf < 4; nf++) {
                ushort4 o4;
                o4.x = f2bf(of[qb2][nf][0] * rl);
                o4.y = f2bf(of[qb2][nf][1] * rl);
                o4.z = f2bf(of[qb2][nf][2] * rl);
                o4.w = f2bf(of[qb2][nf][3] * rl);
                *(ushort4*)(out + orow * ND + h * NHD + nf * 16 + 4 * g) = o4;
            }
        }
    }
}

// ---------------------------------------------------------------------------
extern "C" void kernel_launch(void* const* d_in, const int* in_sizes, int n_in,
                              void* d_out, int out_size, void* d_ws, size_t ws_size,
                              hipStream_t stream) {
    const float* x     = (const float*)d_in[0];
    const float* ln1_g = (const float*)d_in[1];
    const float* ln1_b = (const float*)d_in[2];
    const float* ln2_g = (const float*)d_in[3];
    const float* ln2_b = (const float*)d_in[4];
    const float* Wq    = (const float*)d_in[5];
    const float* Wk    = (const float*)d_in[6];
    const float* Wv    = (const float*)d_in[7];
    const float* Wo    = (const float*)d_in[8];
    const float* bo    = (const float*)d_in[9];
    const float* W1    = (const float*)d_in[10];
    const float* b1    = (const float*)d_in[11];
    const float* W2    = (const float*)d_in[12];
    const float* b2    = (const float*)d_in[13];
    float* outp = (float*)d_out;

    char* w = (char*)d_ws;
    ushort_t* Wqkv_t = (ushort_t*)(w);                    // 6 MiB  (3072x1024)
    ushort_t* Wo_t   = (ushort_t*)(w + 6291456);          // 2 MiB  (1024x1024)
    ushort_t* W1_t   = (ushort_t*)(w + 8388608);          // 8 MiB  (4096x1024)
    ushort_t* W2_t   = (ushort_t*)(w + 16777216);         // 8 MiB  (1024x4096)
    ushort_t* xn     = (ushort_t*)(w + 25165824);         // 16 MiB (8192x1024), also hn
    ushort_t* qkv    = (ushort_t*)(w + 41943040);         // 48 MiB (8192x3072; V third unused)
    ushort_t* attn_o = qkv + (size_t)MTOK * 3072;         // 16 MiB (8192x1024)
    ushort_t* ff1    = qkv;                               // 64 MiB (8192x4096) reuse
    ushort_t* hbuf   = (ushort_t*)(w + 41943040 + 67108864);      // 16 MiB (bf16)
    ushort_t* vT     = (ushort_t*)(w + 41943040 + 67108864 + 16777216); // 16 MiB (4096x2048)

    dim3 tb(32, 8);
    transpose_qkv_to_bf16<<<dim3(2, 32, 48), tb, 0, stream>>>(Wq, Wk, Wv, Wqkv_t);
    transpose_to_bf16<<<dim3(32, 32), tb, 0, stream>>>(Wo, Wo_t, 1024, 1024);
    transpose_to_bf16<<<dim3(128, 32), tb, 0, stream>>>(W1, W1_t, 1024, 4096);
    transpose_to_bf16<<<dim3(32, 128), tb, 0, stream>>>(W2, W2_t, 4096, 1024);

    layernorm_to_bf16<<<MTOK, 256, 0, stream>>>(x, ln1_g, ln1_b, xn);

    // QKV via gemm2b64 (2 blocks/CU overlap): Q,K row-major; V -> vT transposed
    gemm2b64<false, false, 0, false, 1><<<dim3(24, 64), 256, 0, stream>>>(
        xn, Wqkv_t, nullptr, nullptr, qkv, vT, MTOK, 3072, 1024);

    attn_kernel<<<dim3(8, 64), 256, 0, stream>>>(qkv, vT, attn_o);

    // Wo via gemm2b64: h = attn@Wo + bo + x (bf16 out)
    gemm2b64<true, false, 1, false><<<dim3(8, 64), 256, 0, stream>>>(
        attn_o, Wo_t, bo, x, hbuf, nullptr, MTOK, 1024, 1024);

    layernorm_bf16<<<MTOK, 256, 0, stream>>>(hbuf, ln2_g, ln2_b, xn);

    // FFN1: 256x256 gemm8p
    gemm8p<true, true, 0, false><<<dim3(16, 32), 512, 0, stream>>>(
        xn, W1_t, b1, nullptr, ff1, MTOK, NF, 1024);

    // FFN2: N=1024, K=4096 -> gemm2b64
    gemm2b64<true, false, 2, true><<<dim3(8, 64), 256, 0, stream>>>(
        ff1, W2_t, b2, hbuf, outp, nullptr, MTOK, 1024, NF);
}

// Round 19
// 344.602 us; speedup vs baseline: 1.0011x; 1.0011x over previous
//
#include <hip/hip_runtime.h>
#include <hip/hip_bf16.h>

#define NB 4
#define NT 2048
#define ND 1024
#define NH 16
#define NHD 64
#define NF 4096
#define MTOK (NB*NT)  // 8192

typedef float f32x4 __attribute__((ext_vector_type(4)));
typedef __bf16 bf16x8 __attribute__((ext_vector_type(8)));
typedef short s16x8 __attribute__((ext_vector_type(8)));
typedef unsigned short ushort_t;

__device__ inline ushort_t f2bf(float f) {
    unsigned int u = __builtin_bit_cast(unsigned int, f);
    unsigned int r = (u + 0x7FFFu + ((u >> 16) & 1u)) >> 16;
    return (ushort_t)r;
}
__device__ inline float bf2f(ushort_t u) {
    return __builtin_bit_cast(float, (unsigned int)u << 16);
}

__device__ __forceinline__ void async_load16(const void* g, void* l) {
    __builtin_amdgcn_global_load_lds(
        (const __attribute__((address_space(1))) void*)g,
        (__attribute__((address_space(3))) void*)l, 16, 0, 0);
}

__device__ __forceinline__ unsigned int cvt_pk_bf16(float lo, float hi) {
    unsigned int r;
    asm("v_cvt_pk_bf16_f32 %0, %1, %2" : "=v"(r) : "v"(lo), "v"(hi));
    return r;
}

__device__ __forceinline__ float exp2_fast(float x) {
    float r;
    asm("v_exp_f32 %0, %1" : "=v"(r) : "v"(x));
    return r;
}

// ---------------------------------------------------------------------------
// Transpose-convert: src fp32 (R x C) row-major -> dst bf16 (C x R) row-major
// ---------------------------------------------------------------------------
__global__ __launch_bounds__(256)
void transpose_to_bf16(const float* __restrict__ src, ushort_t* __restrict__ dst,
                       int R, int C) {
    __shared__ float tile[32][33];
    int c0 = blockIdx.x * 32, r0 = blockIdx.y * 32;
    #pragma unroll
    for (int i = 0; i < 32; i += 8)
        tile[threadIdx.y + i][threadIdx.x] =
            src[(size_t)(r0 + threadIdx.y + i) * C + c0 + threadIdx.x];
    __syncthreads();
    #pragma unroll
    for (int i = 0; i < 32; i += 8)
        dst[(size_t)(c0 + threadIdx.y + i) * R + r0 + threadIdx.x] =
            f2bf(tile[threadIdx.x][threadIdx.y + i]);
}

// QKV weights: Wq/Wk/Wv are (H, D, HD). Build Bt (3072 x 1024) bf16.
// Wq pre-scaled by (1/32)*log2(e): QK^T scores come out in exp2 domain.
__global__ __launch_bounds__(256)
void transpose_qkv_to_bf16(const float* __restrict__ Wq, const float* __restrict__ Wk,
                           const float* __restrict__ Wv, ushort_t* __restrict__ dst) {
    __shared__ float tile[32][33];
    int z = blockIdx.z;            // 0..47
    int w = z >> 4, h = z & 15;
    const float* src = (w == 0 ? Wq : (w == 1 ? Wk : Wv)) + (size_t)h * ND * NHD;
    const float sc = (w == 0) ? 0.03125f * 1.44269504f : 1.0f;
    ushort_t* out = dst + ((size_t)w * ND + h * NHD) * ND;
    int c0 = blockIdx.x * 32, r0 = blockIdx.y * 32;
    #pragma unroll
    for (int i = 0; i < 32; i += 8)
        tile[threadIdx.y + i][threadIdx.x] =
            src[(size_t)(r0 + threadIdx.y + i) * NHD + c0 + threadIdx.x];
    __syncthreads();
    #pragma unroll
    for (int i = 0; i < 32; i += 8)
        out[(size_t)(c0 + threadIdx.y + i) * ND + r0 + threadIdx.x] =
            f2bf(tile[threadIdx.x][threadIdx.y + i] * sc);
}

// ---------------------------------------------------------------------------
// LayerNorm (rows of 1024 fp32) -> bf16 out
// ---------------------------------------------------------------------------
__global__ __launch_bounds__(256)
void layernorm_to_bf16(const float* __restrict__ x, const float* __restrict__ g,
                       const float* __restrict__ bvec, ushort_t* __restrict__ out) {
    int row = blockIdx.x;
    const float4* xr = (const float4*)(x + (size_t)row * ND);
    float4 v = xr[threadIdx.x];
    float s = v.x + v.y + v.z + v.w;
    float s2 = v.x * v.x + v.y * v.y + v.z * v.z + v.w * v.w;
    #pragma unroll
    for (int o = 32; o >= 1; o >>= 1) {
        s += __shfl_xor(s, o);
        s2 += __shfl_xor(s2, o);
    }
    __shared__ float red[8];
    int wave = threadIdx.x >> 6, lane = threadIdx.x & 63;
    if (lane == 0) { red[wave] = s; red[4 + wave] = s2; }
    __syncthreads();
    float ts = red[0] + red[1] + red[2] + red[3];
    float ts2 = red[4] + red[5] + red[6] + red[7];
    float mu = ts * (1.f / ND);
    float var = ts2 * (1.f / ND) - mu * mu;
    float rs = rsqrtf(var + 1e-5f);
    float4 gv = ((const float4*)g)[threadIdx.x];
    float4 bv = ((const float4*)bvec)[threadIdx.x];
    ushort4 o4;
    o4.x = f2bf((v.x - mu) * rs * gv.x + bv.x);
    o4.y = f2bf((v.y - mu) * rs * gv.y + bv.y);
    o4.z = f2bf((v.z - mu) * rs * gv.z + bv.z);
    o4.w = f2bf((v.w - mu) * rs * gv.w + bv.w);
    ((ushort4*)(out + (size_t)row * ND))[threadIdx.x] = o4;
}

// LayerNorm on bf16 input (rows of 1024) -> bf16 out
__global__ __launch_bounds__(256)
void layernorm_bf16(const ushort_t* __restrict__ x, const float* __restrict__ g,
                    const float* __restrict__ bvec, ushort_t* __restrict__ out) {
    int row = blockIdx.x;
    ushort4 u4 = ((const ushort4*)(x + (size_t)row * ND))[threadIdx.x];
    float4 v;
    v.x = bf2f(u4.x); v.y = bf2f(u4.y); v.z = bf2f(u4.z); v.w = bf2f(u4.w);
    float s = v.x + v.y + v.z + v.w;
    float s2 = v.x * v.x + v.y * v.y + v.z * v.z + v.w * v.w;
    #pragma unroll
    for (int o = 32; o >= 1; o >>= 1) {
        s += __shfl_xor(s, o);
        s2 += __shfl_xor(s2, o);
    }
    __shared__ float red[8];
    int wave = threadIdx.x >> 6, lane = threadIdx.x & 63;
    if (lane == 0) { red[wave] = s; red[4 + wave] = s2; }
    __syncthreads();
    float ts = red[0] + red[1] + red[2] + red[3];
    float ts2 = red[4] + red[5] + red[6] + red[7];
    float mu = ts * (1.f / ND);
    float var = ts2 * (1.f / ND) - mu * mu;
    float rs = rsqrtf(var + 1e-5f);
    float4 gv = ((const float4*)g)[threadIdx.x];
    float4 bv = ((const float4*)bvec)[threadIdx.x];
    ushort4 o4;
    o4.x = f2bf((v.x - mu) * rs * gv.x + bv.x);
    o4.y = f2bf((v.y - mu) * rs * gv.y + bv.y);
    o4.z = f2bf((v.z - mu) * rs * gv.z + bv.z);
    o4.w = f2bf((v.w - mu) * rs * gv.w + bv.w);
    ((ushort4*)(out + (size_t)row * ND))[threadIdx.x] = o4;
}

// ---------------------------------------------------------------------------
// gemm8p: 256x256 tile, BK=64, 4 phases/tile, counted vmcnt(6) at q3.
// (FFN1 path — verified.)
// ---------------------------------------------------------------------------
template<bool HAS_BIAS, bool RELU, int RES_MODE, bool OUT_F32>
__global__ __launch_bounds__(512, 2)
void gemm8p(const ushort_t* __restrict__ A, const ushort_t* __restrict__ Bt,
            const float* __restrict__ bias, const void* __restrict__ res,
            void* __restrict__ outp, int M, int N, int K) {
    constexpr int BN = 256;
    constexpr int NFR = BN / 64;
    __shared__ __align__(16) ushort_t As[2][256 * 64];
    __shared__ __align__(16) ushort_t Bs[2][BN * 64];
    const int t = threadIdx.x;
    const int wave = t >> 6, lane = t & 63;
    const int wm = wave >> 2, wn = wave & 3;
    const int g = lane >> 4, l16 = lane & 15;
    int wid = blockIdx.y * gridDim.x + blockIdx.x;
    const int cpx = (gridDim.x * gridDim.y) >> 3;
    wid = (wid & 7) * cpx + (wid >> 3);
    const int m0 = (wid / gridDim.x) * 256;
    const int n0 = (wid % gridDim.x) * BN;
    const int lrow8 = lane >> 3;
    const int srcCol = ((lane & 7) ^ lrow8) * 8;
    const ushort_t* Abase = A + (size_t)m0 * K + srcCol;
    const ushort_t* Bbase = Bt + (size_t)n0 * K + srcCol;
    const int NKT = K >> 6;

    f32x4 acc[8][NFR] = {};

    auto stageAhalf = [&](int kt, int h, int slot) {
        #pragma unroll
        for (int j = 2 * h; j < 2 * h + 2; j++) {
            const int rowbase = j * 64 + wave * 8;
            async_load16(Abase + (size_t)(rowbase + lrow8) * K + kt * 64,
                         &As[slot][rowbase * 64]);
        }
    };
    auto stageBhalf = [&](int kt, int h, int slot) {
        #pragma unroll
        for (int j = 2 * h; j < 2 * h + 2; j++) {
            const int rowbase = j * 64 + wave * 8;
            async_load16(Bbase + (size_t)(rowbase + lrow8) * K + kt * 64,
                         &Bs[slot][rowbase * 64]);
        }
    };

    stageAhalf(0, 0, 0); stageAhalf(0, 1, 0);
    stageBhalf(0, 0, 0); stageBhalf(0, 1, 0);
    stageBhalf(1, 0, 1); stageBhalf(1, 1, 1);
    stageAhalf(1, 0, 1);
    asm volatile("s_waitcnt vmcnt(6)" ::: "memory");
    __builtin_amdgcn_s_barrier();
    __builtin_amdgcn_sched_barrier(0);

    for (int kt = 0; kt < NKT; ++kt) {
        const int cur = kt & 1, nxt = cur ^ 1;
        const ushort_t* as = As[cur];
        const ushort_t* bs = Bs[cur];
        bf16x8 bfr[NFR][2];
        #pragma unroll
        for (int q = 0; q < 4; q++) {
            if (q == 0) {
                #pragma unroll
                for (int nf = 0; nf < NFR; nf++)
                    #pragma unroll
                    for (int ks = 0; ks < 2; ks++) {
                        const int row = wn * (BN / 4) + nf * 16 + l16;
                        int a = row * 128 + ks * 64 + 16 * g;
                        a ^= (row & 7) << 4;
                        bfr[nf][ks] = *(const bf16x8*)((const char*)bs + a);
                    }
            }
            bf16x8 af[2][2];
            #pragma unroll
            for (int mi2 = 0; mi2 < 2; mi2++)
                #pragma unroll
                for (int ks = 0; ks < 2; ks++) {
                    const int row = q * 64 + wm * 32 + mi2 * 16 + l16;
                    int a = row * 128 + ks * 64 + 16 * g;
                    a ^= (row & 7) << 4;
                    af[mi2][ks] = *(const bf16x8*)((const char*)as + a);
                }
            if (q == 0)      { if (kt + 1 < NKT) stageAhalf(kt + 1, 1, nxt); }
            else if (q == 1) { if (kt + 2 < NKT) stageBhalf(kt + 2, 0, cur); }
            else if (q == 2) { if (kt + 2 < NKT) stageBhalf(kt + 2, 1, cur); }
            else             { if (kt + 2 < NKT) stageAhalf(kt + 2, 0, cur); }
            __builtin_amdgcn_sched_barrier(0);
            if (q == 3) {
                if (kt >= NKT - 2) asm volatile("s_waitcnt vmcnt(0)" ::: "memory");
                else               asm volatile("s_waitcnt vmcnt(6)" ::: "memory");
            }
            __builtin_amdgcn_s_barrier();
            __builtin_amdgcn_sched_barrier(0);
            __builtin_amdgcn_s_setprio(1);
            #pragma unroll
            for (int mi2 = 0; mi2 < 2; mi2++)
                #pragma unroll
                for (int nf = 0; nf < NFR; nf++)
                    #pragma unroll
                    for (int ks = 0; ks < 2; ks++)
                        acc[q * 2 + mi2][nf] = __builtin_amdgcn_mfma_f32_16x16x32_bf16(
                            af[mi2][ks], bfr[nf][ks], acc[q * 2 + mi2][nf], 0, 0, 0);
            __builtin_amdgcn_s_setprio(0);
            __builtin_amdgcn_s_barrier();
            __builtin_amdgcn_sched_barrier(0);
        }
    }

    const int gc0 = n0 + wn * (BN / 4) + l16;
    #pragma unroll
    for (int mi = 0; mi < 8; mi++) {
        const int rowb = m0 + (mi >> 1) * 64 + wm * 32 + (mi & 1) * 16 + g * 4;
        #pragma unroll
        for (int nf = 0; nf < NFR; nf++) {
            const int col = gc0 + nf * 16;
            float bb = 0.f;
            if constexpr (HAS_BIAS) bb = bias[col];
            #pragma unroll
            for (int r = 0; r < 4; r++) {
                const int row = rowb + r;
                float v = acc[mi][nf][r] + bb;
                if constexpr (RELU) v = fmaxf(v, 0.f);
                if constexpr (RES_MODE == 1)
                    v += ((const float*)res)[(size_t)row * N + col];
                else if constexpr (RES_MODE == 2)
                    v += bf2f(((const ushort_t*)res)[(size_t)row * N + col]);
                if constexpr (OUT_F32)
                    ((float*)outp)[(size_t)row * N + col] = v;
                else
                    ((ushort_t*)outp)[(size_t)row * N + col] = f2bf(v);
            }
        }
    }
}

// ---------------------------------------------------------------------------
// gemm2b64: 128x128 tile, BK=64, 2 blocks/CU cross-block overlap (round-15
// verified). Counted vmcnt(8); (row&7)<<4 swizzle; 0 conflicts.
// OUT_MODE: 0 normal; 1 qkv-split (n0>=2048 -> V transposed into vTp).
// ---------------------------------------------------------------------------
template<bool HAS_BIAS, bool RELU, int RES_MODE, bool OUT_F32, int OUT_MODE = 0>
__global__ __launch_bounds__(256, 2)
void gemm2b64(const ushort_t* __restrict__ A, const ushort_t* __restrict__ Bt,
              const float* __restrict__ bias, const void* __restrict__ res,
              void* __restrict__ outp, ushort_t* __restrict__ vTp,
              int M, int N, int K) {
    __shared__ __align__(16) ushort_t As[2][128 * 64];
    __shared__ __align__(16) ushort_t Bs[2][128 * 64];
    const int t = threadIdx.x;
    const int wave = t >> 6, lane = t & 63;
    const int wm = wave >> 1, wn = wave & 1;        // 2M x 2N
    const int g = lane >> 4, l16 = lane & 15;
    int wid = blockIdx.y * gridDim.x + blockIdx.x;
    const int cpx = (gridDim.x * gridDim.y) >> 3;
    wid = (wid & 7) * cpx + (wid >> 3);
    const int m0 = (wid / gridDim.x) * 128;
    const int n0 = (wid % gridDim.x) * 128;
    const int rw = lane >> 3, ck = lane & 7;        // 8 rows x 8 chunks of 16B
    const int srcCol = (ck ^ rw) * 8;               // pre-swizzled source (ushorts)
    const ushort_t* Abase = A + (size_t)m0 * K + srcCol;
    const ushort_t* Bbase = Bt + (size_t)n0 * K + srcCol;
    const int NKT = K >> 6;

    f32x4 acc[4][4] = {};   // [mi][nf]

    auto stage = [&](int kt, int slot) {
        #pragma unroll
        for (int j = 0; j < 4; j++) {
            const int rowbase = j * 32 + wave * 8;  // wave-uniform
            async_load16(Abase + (size_t)(rowbase + rw) * K + kt * 64,
                         &As[slot][rowbase * 64]);
        }
        #pragma unroll
        for (int j = 0; j < 4; j++) {
            const int rowbase = j * 32 + wave * 8;
            async_load16(Bbase + (size_t)(rowbase + rw) * K + kt * 64,
                         &Bs[slot][rowbase * 64]);
        }
    };

    stage(0, 0);
    stage(1, 1);

    for (int kt = 0; kt < NKT; ++kt) {
        const int cur = kt & 1;
        if (kt >= NKT - 1) asm volatile("s_waitcnt vmcnt(0)" ::: "memory");
        else               asm volatile("s_waitcnt vmcnt(8)" ::: "memory");
        __builtin_amdgcn_s_barrier();
        __builtin_amdgcn_sched_barrier(0);

        const ushort_t* as = As[cur];
        const ushort_t* bs = Bs[cur];
        bf16x8 af[4][2], bfr[4][2];
        #pragma unroll
        for (int mi = 0; mi < 4; mi++)
            #pragma unroll
            for (int ks = 0; ks < 2; ks++) {
                const int row = wm * 64 + mi * 16 + l16;
                int a = row * 128 + ks * 64 + 16 * g;
                a ^= (row & 7) << 4;
                af[mi][ks] = *(const bf16x8*)((const char*)as + a);
            }
        #pragma unroll
        for (int nf = 0; nf < 4; nf++)
            #pragma unroll
            for (int ks = 0; ks < 2; ks++) {
                const int row = wn * 64 + nf * 16 + l16;
                int a = row * 128 + ks * 64 + 16 * g;
                a ^= (row & 7) << 4;
                bfr[nf][ks] = *(const bf16x8*)((const char*)bs + a);
            }
        __builtin_amdgcn_s_setprio(1);
        #pragma unroll
        for (int mi = 0; mi < 4; mi++)
            #pragma unroll
            for (int nf = 0; nf < 4; nf++)
                #pragma unroll
                for (int ks = 0; ks < 2; ks++)
                    acc[mi][nf] = __builtin_amdgcn_mfma_f32_16x16x32_bf16(
                        af[mi][ks], bfr[nf][ks], acc[mi][nf], 0, 0, 0);
        __builtin_amdgcn_s_setprio(0);
        __builtin_amdgcn_s_barrier();
        __builtin_amdgcn_sched_barrier(0);
        if (kt + 2 < NKT) stage(kt + 2, cur);
    }

    const int gc0 = n0 + wn * 64 + l16;
    if constexpr (OUT_MODE == 1) {
        if (n0 >= 2048) {
            // V -> transposed store: vT[b*1024 + (col-2048)][t], 4 t's per store
            #pragma unroll
            for (int mi = 0; mi < 4; mi++) {
                const int rowb = m0 + wm * 64 + mi * 16 + g * 4;
                const int b = rowb >> 11, tt = rowb & 2047;
                #pragma unroll
                for (int nf = 0; nf < 4; nf++) {
                    const int col = gc0 + nf * 16;
                    ushort4 o4;
                    o4.x = f2bf(acc[mi][nf][0]);
                    o4.y = f2bf(acc[mi][nf][1]);
                    o4.z = f2bf(acc[mi][nf][2]);
                    o4.w = f2bf(acc[mi][nf][3]);
                    *(ushort4*)(vTp + (size_t)(b * 1024 + col - 2048) * NT + tt) = o4;
                }
            }
            return;
        }
    }
    #pragma unroll
    for (int mi = 0; mi < 4; mi++) {
        const int rowb = m0 + wm * 64 + mi * 16 + g * 4;
        #pragma unroll
        for (int nf = 0; nf < 4; nf++) {
            const int col = gc0 + nf * 16;
            float bb = 0.f;
            if constexpr (HAS_BIAS) bb = bias[col];
            #pragma unroll
            for (int r = 0; r < 4; r++) {
                const int row = rowb + r;
                float v = acc[mi][nf][r] + bb;
                if constexpr (RELU) v = fmaxf(v, 0.f);
                if constexpr (RES_MODE == 1)
                    v += ((const float*)res)[(size_t)row * N + col];
                else if constexpr (RES_MODE == 2)
                    v += bf2f(((const ushort_t*)res)[(size_t)row * N + col]);
                if constexpr (OUT_F32)
                    ((float*)outp)[(size_t)row * N + col] = v;
                else
                    ((ushort_t*)outp)[(size_t)row * N + col] = f2bf(v);
            }
        }
    }
}

// ---------------------------------------------------------------------------
// Causal flash attention, no max-tracking; row-sum via ones-MFMA. V arrives
// pre-transposed (vT, written by the QKV GEMM) and is staged like K via
// global_load_lds (source pre-swizzled by c(d)=(d&7)^(d>>3)). P round-trip
// through Pw is VECTORIZED: 36-word row stride (144B = 16B-aligned rows) ->
// 8 ds_write_b64 + 4 ds_read_b128 per wave-iter (was 32 scalar b32 ops).
// QBLK=128: 4 waves x 32 q-rows. Grid (8,64)=512 = 2 blocks/CU.
// ---------------------------------------------------------------------------
__global__ __launch_bounds__(256)
void attn_kernel(const ushort_t* __restrict__ qkv, const ushort_t* __restrict__ vT,
                 ushort_t* __restrict__ out) {
    __shared__ __align__(16) ushort_t Ks[2][64 * 64];  // linear, XOR-swizzle on read
    __shared__ __align__(16) ushort_t Vt[2][64 * 64];  // d-major, XOR-swizzled
    __shared__ __align__(16) unsigned int Pw[4][32][36];  // per-wave P words
    const int L = blockIdx.y * gridDim.x + blockIdx.x; // grid (8,64) -> 512
    const int xcd = L & 7, kk = L >> 3;
    const int bh = ((kk & 7) << 3) | xcd;              // 8 pair-blocks of bh -> one XCD
    const int pairIdx = kk >> 3;                       // 0..7
    const int b = bh >> 4, h = bh & 15;
    const int t = threadIdx.x, wave = t >> 6, lane = t & 63;
    const int g = lane >> 4, q16 = lane & 15;
    const size_t base = ((size_t)b * NT) * 3072 + h * NHD;
    const ushort_t* qp_base = qkv + base;
    const ushort_t* kb = qkv + base + 1024;
    const ushort_t* vbt = vT + (size_t)bh * 64 * NT;   // rows d, length NT
    const int krw = lane >> 3, kck = lane & 7;
    const int ksrc = (kck ^ krw) * 8;                  // pre-swizzled source column

    bf16x8 ones_f;
    {
        uint4 u = {0x3F803F80u, 0x3F803F80u, 0x3F803F80u, 0x3F803F80u};
        ones_f = __builtin_bit_cast(bf16x8, u);
    }

    auto stageK = [&](int kv, int buf) {
        #pragma unroll
        for (int c = 0; c < 2; c++) {
            const int rowbase = c * 32 + wave * 8;     // wave-uniform
            async_load16(kb + (size_t)(kv * 64 + rowbase + krw) * 3072 + ksrc,
                         &Ks[buf][rowbase * 64]);
        }
    };
    auto stageV = [&](int kv, int buf) {
        #pragma unroll
        for (int c = 0; c < 2; c++) {
            const int rowbase = c * 32 + wave * 8;     // wave-uniform
            const int scol = ((kck ^ krw ^ ((c * 4 + wave) & 7)) * 8);
            async_load16(vbt + (size_t)(rowbase + krw) * NT + kv * 64 + scol,
                         &Vt[buf][rowbase * 64]);
        }
    };

    for (int half = 0; half < 2; half++) {
        const int qt = half ? (15 - pairIdx) : pairIdx;
        const int q0 = qt * 128;
        const int wq0 = q0 + wave * 32;
        bf16x8 qf[2][2];
        #pragma unroll
        for (int qb2 = 0; qb2 < 2; qb2++) {
            const ushort_t* qp = qp_base + (size_t)(wq0 + 16 * qb2 + q16) * 3072 + 8 * g;
            qf[qb2][0] = *(const bf16x8*)qp;
            qf[qb2][1] = *(const bf16x8*)(qp + 32);
        }
        f32x4 of[2][4] = {};
        f32x4 of4[2] = {};               // row-sum accumulator (l), via ones-MFMA
        const int nkv = 2 * qt + 2;

        stageK(0, 0);
        stageV(0, 0);
        __syncthreads();                 // drains vmcnt before first use

        for (int kv = 0; kv < nkv; ++kv) {
            const int cur = kv & 1, nxt = cur ^ 1;
            if (kv + 1 < nkv) {
                stageK(kv + 1, nxt);
                stageV(kv + 1, nxt);
            }
            __builtin_amdgcn_sched_barrier(0);   // pin prefetch issue before compute

            const int kbase = kv * 64;
            if (kbase <= wq0 + 31) {
                bf16x8 kf[4][2];
                #pragma unroll
                for (int n = 0; n < 4; n++)
                    #pragma unroll
                    for (int kd = 0; kd < 2; kd++) {
                        int row = n * 16 + q16;
                        int a = row * 128 + (kd * 64 + 16 * g);
                        a ^= ((row & 7) << 4);
                        kf[n][kd] = *(const bf16x8*)((const char*)&Ks[cur][0] + a);
                    }

                f32x4 sf[2][4] = {};
                #pragma unroll
                for (int n = 0; n < 4; n++)
                    #pragma unroll
                    for (int kd = 0; kd < 2; kd++) {
                        sf[0][n] = __builtin_amdgcn_mfma_f32_16x16x32_bf16(
                            kf[n][kd], qf[0][kd], sf[0][n], 0, 0, 0);
                        sf[1][n] = __builtin_amdgcn_mfma_f32_16x16x32_bf16(
                            kf[n][kd], qf[1][kd], sf[1][n], 0, 0, 0);
                    }

                #pragma unroll
                for (int qb2 = 0; qb2 < 2; qb2++) {
                    const int wqb = wq0 + 16 * qb2 + q16;
                    const bool partial = (kbase + 63 > wq0 + 16 * qb2);
                    float p[4][4];
                    #pragma unroll
                    for (int n = 0; n < 4; n++)
                        #pragma unroll
                        for (int r = 0; r < 4; r++) {
                            float v = sf[qb2][n][r];
                            if (partial) {
                                int kg = kbase + n * 16 + 4 * g + r;
                                if (kg > wqb) v = -1.0e30f;   // exp2 -> 0
                            }
                            p[n][r] = exp2_fast(v);
                        }
                    unsigned int* pr = &Pw[wave][16 * qb2 + q16][0];
                    #pragma unroll
                    for (int n = 0; n < 4; n++) {
                        uint2 wv;
                        wv.x = cvt_pk_bf16(p[n][0], p[n][1]);
                        wv.y = cvt_pk_bf16(p[n][2], p[n][3]);
                        *(uint2*)(pr + 8 * n + 2 * g) = wv;   // 8B-aligned
                    }
                }

                #pragma unroll
                for (int kbk = 0; kbk < 2; kbk++) {
                    bf16x8 pfr[2];
                    #pragma unroll
                    for (int qb2 = 0; qb2 < 2; qb2++) {
                        const unsigned int* pr = &Pw[wave][16 * qb2 + q16][0];
                        uint4 pu = *(const uint4*)(pr + 16 * kbk + 4 * g);  // 16B-aligned
                        pfr[qb2] = __builtin_bit_cast(bf16x8, pu);
                    }
                    of4[0] = __builtin_amdgcn_mfma_f32_16x16x32_bf16(
                        ones_f, pfr[0], of4[0], 0, 0, 0);
                    of4[1] = __builtin_amdgcn_mfma_f32_16x16x32_bf16(
                        ones_f, pfr[1], of4[1], 0, 0, 0);
                    #pragma unroll
                    for (int nf = 0; nf < 4; nf++) {
                        const int d = nf * 16 + q16;
                        int a = (d << 7) + (kbk * 64 + 16 * g);
                        a ^= (((d & 7) ^ ((d >> 3) & 7)) << 4);
                        bf16x8 vf = *(const bf16x8*)((const char*)&Vt[cur][0] + a);
                        of[0][nf] = __builtin_amdgcn_mfma_f32_16x16x32_bf16(
                            vf, pfr[0], of[0][nf], 0, 0, 0);
                        of[1][nf] = __builtin_amdgcn_mfma_f32_16x16x32_bf16(
                            vf, pfr[1], of[1][nf], 0, 0, 0);
                    }
                }
            }

            __syncthreads();   // drains K+V prefetch + buffer handoff
        }

        #pragma unroll
        for (int qb2 = 0; qb2 < 2; qb2++) {
            float rl = 1.f / of4[qb2][0];
            const size_t orow = (size_t)b * NT + q0 + wave * 32 + 16 * qb2 + q16;
            #pragma unroll
            for (int nf = 0; nf < 4; nf++) {
                ushort4 o4;
                o4.x = f2bf(of[qb2][nf][0] * rl);
                o4.y = f2bf(of[qb2][nf][1] * rl);
                o4.z = f2bf(of[qb2][nf][2] * rl);
                o4.w = f2bf(of[qb2][nf][3] * rl);
                *(ushort4*)(out + orow * ND + h * NHD + nf * 16 + 4 * g) = o4;
            }
        }
    }
}

// ---------------------------------------------------------------------------
extern "C" void kernel_launch(void* const* d_in, const int* in_sizes, int n_in,
                              void* d_out, int out_size, void* d_ws, size_t ws_size,
                              hipStream_t stream) {
    const float* x     = (const float*)d_in[0];
    const float* ln1_g = (const float*)d_in[1];
    const float* ln1_b = (const float*)d_in[2];
    const float* ln2_g = (const float*)d_in[3];
    const float* ln2_b = (const float*)d_in[4];
    const float* Wq    = (const float*)d_in[5];
    const float* Wk    = (const float*)d_in[6];
    const float* Wv    = (const float*)d_in[7];
    const float* Wo    = (const float*)d_in[8];
    const float* bo    = (const float*)d_in[9];
    const float* W1    = (const float*)d_in[10];
    const float* b1    = (const float*)d_in[11];
    const float* W2    = (const float*)d_in[12];
    const float* b2    = (const float*)d_in[13];
    float* outp = (float*)d_out;

    char* w = (char*)d_ws;
    ushort_t* Wqkv_t = (ushort_t*)(w);                    // 6 MiB  (3072x1024)
    ushort_t* Wo_t   = (ushort_t*)(w + 6291456);          // 2 MiB  (1024x1024)
    ushort_t* W1_t   = (ushort_t*)(w + 8388608);          // 8 MiB  (4096x1024)
    ushort_t* W2_t   = (ushort_t*)(w + 16777216);         // 8 MiB  (1024x4096)
    ushort_t* xn     = (ushort_t*)(w + 25165824);         // 16 MiB (8192x1024), also hn
    ushort_t* qkv    = (ushort_t*)(w + 41943040);         // 48 MiB (8192x3072; V third unused)
    ushort_t* attn_o = qkv + (size_t)MTOK * 3072;         // 16 MiB (8192x1024)
    ushort_t* ff1    = qkv;                               // 64 MiB (8192x4096) reuse
    ushort_t* hbuf   = (ushort_t*)(w + 41943040 + 67108864);      // 16 MiB (bf16)
    ushort_t* vT     = (ushort_t*)(w + 41943040 + 67108864 + 16777216); // 16 MiB (4096x2048)

    dim3 tb(32, 8);
    transpose_qkv_to_bf16<<<dim3(2, 32, 48), tb, 0, stream>>>(Wq, Wk, Wv, Wqkv_t);
    transpose_to_bf16<<<dim3(32, 32), tb, 0, stream>>>(Wo, Wo_t, 1024, 1024);
    transpose_to_bf16<<<dim3(128, 32), tb, 0, stream>>>(W1, W1_t, 1024, 4096);
    transpose_to_bf16<<<dim3(32, 128), tb, 0, stream>>>(W2, W2_t, 4096, 1024);

    layernorm_to_bf16<<<MTOK, 256, 0, stream>>>(x, ln1_g, ln1_b, xn);

    // QKV via gemm2b64 (2 blocks/CU overlap): Q,K row-major; V -> vT transposed
    gemm2b64<false, false, 0, false, 1><<<dim3(24, 64), 256, 0, stream>>>(
        xn, Wqkv_t, nullptr, nullptr, qkv, vT, MTOK, 3072, 1024);

    attn_kernel<<<dim3(8, 64), 256, 0, stream>>>(qkv, vT, attn_o);

    // Wo via gemm2b64: h = attn@Wo + bo + x (bf16 out)
    gemm2b64<true, false, 1, false><<<dim3(8, 64), 256, 0, stream>>>(
        attn_o, Wo_t, bo, x, hbuf, nullptr, MTOK, 1024, 1024);

    layernorm_bf16<<<MTOK, 256, 0, stream>>>(hbuf, ln2_g, ln2_b, xn);

    // FFN1: 256x256 gemm8p
    gemm8p<true, true, 0, false><<<dim3(16, 32), 512, 0, stream>>>(
        xn, W1_t, b1, nullptr, ff1, MTOK, NF, 1024);

    // FFN2: N=1024, K=4096 -> gemm2b64
    gemm2b64<true, false, 2, true><<<dim3(8, 64), 256, 0, stream>>>(
        ff1, W2_t, b2, hbuf, outp, nullptr, MTOK, 1024, NF);
}

// Round 20
// 341.494 us; speedup vs baseline: 1.0102x; 1.0091x over previous
//
#include <hip/hip_runtime.h>
#include <hip/hip_bf16.h>

#define NB 4
#define NT 2048
#define ND 1024
#define NH 16
#define NHD 64
#define NF 4096
#define MTOK (NB*NT)  // 8192

typedef float f32x4 __attribute__((ext_vector_type(4)));
typedef __bf16 bf16x8 __attribute__((ext_vector_type(8)));
typedef short s16x8 __attribute__((ext_vector_type(8)));
typedef unsigned short ushort_t;

__device__ inline ushort_t f2bf(float f) {
    unsigned int u = __builtin_bit_cast(unsigned int, f);
    unsigned int r = (u + 0x7FFFu + ((u >> 16) & 1u)) >> 16;
    return (ushort_t)r;
}
__device__ inline float bf2f(ushort_t u) {
    return __builtin_bit_cast(float, (unsigned int)u << 16);
}

__device__ __forceinline__ void async_load16(const void* g, void* l) {
    __builtin_amdgcn_global_load_lds(
        (const __attribute__((address_space(1))) void*)g,
        (__attribute__((address_space(3))) void*)l, 16, 0, 0);
}

__device__ __forceinline__ unsigned int cvt_pk_bf16(float lo, float hi) {
    unsigned int r;
    asm("v_cvt_pk_bf16_f32 %0, %1, %2" : "=v"(r) : "v"(lo), "v"(hi));
    return r;
}

__device__ __forceinline__ float exp2_fast(float x) {
    float r;
    asm("v_exp_f32 %0, %1" : "=v"(r) : "v"(x));
    return r;
}

// ---------------------------------------------------------------------------
// Transpose-convert: src fp32 (R x C) row-major -> dst bf16 (C x R) row-major
// ---------------------------------------------------------------------------
__global__ __launch_bounds__(256)
void transpose_to_bf16(const float* __restrict__ src, ushort_t* __restrict__ dst,
                       int R, int C) {
    __shared__ float tile[32][33];
    int c0 = blockIdx.x * 32, r0 = blockIdx.y * 32;
    #pragma unroll
    for (int i = 0; i < 32; i += 8)
        tile[threadIdx.y + i][threadIdx.x] =
            src[(size_t)(r0 + threadIdx.y + i) * C + c0 + threadIdx.x];
    __syncthreads();
    #pragma unroll
    for (int i = 0; i < 32; i += 8)
        dst[(size_t)(c0 + threadIdx.y + i) * R + r0 + threadIdx.x] =
            f2bf(tile[threadIdx.x][threadIdx.y + i]);
}

// QKV weights: Wq/Wk/Wv are (H, D, HD). Build Bt (3072 x 1024) bf16.
// Wq pre-scaled by (1/32)*log2(e): QK^T scores come out in exp2 domain.
__global__ __launch_bounds__(256)
void transpose_qkv_to_bf16(const float* __restrict__ Wq, const float* __restrict__ Wk,
                           const float* __restrict__ Wv, ushort_t* __restrict__ dst) {
    __shared__ float tile[32][33];
    int z = blockIdx.z;            // 0..47
    int w = z >> 4, h = z & 15;
    const float* src = (w == 0 ? Wq : (w == 1 ? Wk : Wv)) + (size_t)h * ND * NHD;
    const float sc = (w == 0) ? 0.03125f * 1.44269504f : 1.0f;
    ushort_t* out = dst + ((size_t)w * ND + h * NHD) * ND;
    int c0 = blockIdx.x * 32, r0 = blockIdx.y * 32;
    #pragma unroll
    for (int i = 0; i < 32; i += 8)
        tile[threadIdx.y + i][threadIdx.x] =
            src[(size_t)(r0 + threadIdx.y + i) * NHD + c0 + threadIdx.x];
    __syncthreads();
    #pragma unroll
    for (int i = 0; i < 32; i += 8)
        out[(size_t)(c0 + threadIdx.y + i) * ND + r0 + threadIdx.x] =
            f2bf(tile[threadIdx.x][threadIdx.y + i] * sc);
}

// ---------------------------------------------------------------------------
// LayerNorm (rows of 1024 fp32) -> bf16 out
// ---------------------------------------------------------------------------
__global__ __launch_bounds__(256)
void layernorm_to_bf16(const float* __restrict__ x, const float* __restrict__ g,
                       const float* __restrict__ bvec, ushort_t* __restrict__ out) {
    int row = blockIdx.x;
    const float4* xr = (const float4*)(x + (size_t)row * ND);
    float4 v = xr[threadIdx.x];
    float s = v.x + v.y + v.z + v.w;
    float s2 = v.x * v.x + v.y * v.y + v.z * v.z + v.w * v.w;
    #pragma unroll
    for (int o = 32; o >= 1; o >>= 1) {
        s += __shfl_xor(s, o);
        s2 += __shfl_xor(s2, o);
    }
    __shared__ float red[8];
    int wave = threadIdx.x >> 6, lane = threadIdx.x & 63;
    if (lane == 0) { red[wave] = s; red[4 + wave] = s2; }
    __syncthreads();
    float ts = red[0] + red[1] + red[2] + red[3];
    float ts2 = red[4] + red[5] + red[6] + red[7];
    float mu = ts * (1.f / ND);
    float var = ts2 * (1.f / ND) - mu * mu;
    float rs = rsqrtf(var + 1e-5f);
    float4 gv = ((const float4*)g)[threadIdx.x];
    float4 bv = ((const float4*)bvec)[threadIdx.x];
    ushort4 o4;
    o4.x = f2bf((v.x - mu) * rs * gv.x + bv.x);
    o4.y = f2bf((v.y - mu) * rs * gv.y + bv.y);
    o4.z = f2bf((v.z - mu) * rs * gv.z + bv.z);
    o4.w = f2bf((v.w - mu) * rs * gv.w + bv.w);
    ((ushort4*)(out + (size_t)row * ND))[threadIdx.x] = o4;
}

// LayerNorm on bf16 input (rows of 1024) -> bf16 out
__global__ __launch_bounds__(256)
void layernorm_bf16(const ushort_t* __restrict__ x, const float* __restrict__ g,
                    const float* __restrict__ bvec, ushort_t* __restrict__ out) {
    int row = blockIdx.x;
    ushort4 u4 = ((const ushort4*)(x + (size_t)row * ND))[threadIdx.x];
    float4 v;
    v.x = bf2f(u4.x); v.y = bf2f(u4.y); v.z = bf2f(u4.z); v.w = bf2f(u4.w);
    float s = v.x + v.y + v.z + v.w;
    float s2 = v.x * v.x + v.y * v.y + v.z * v.z + v.w * v.w;
    #pragma unroll
    for (int o = 32; o >= 1; o >>= 1) {
        s += __shfl_xor(s, o);
        s2 += __shfl_xor(s2, o);
    }
    __shared__ float red[8];
    int wave = threadIdx.x >> 6, lane = threadIdx.x & 63;
    if (lane == 0) { red[wave] = s; red[4 + wave] = s2; }
    __syncthreads();
    float ts = red[0] + red[1] + red[2] + red[3];
    float ts2 = red[4] + red[5] + red[6] + red[7];
    float mu = ts * (1.f / ND);
    float var = ts2 * (1.f / ND) - mu * mu;
    float rs = rsqrtf(var + 1e-5f);
    float4 gv = ((const float4*)g)[threadIdx.x];
    float4 bv = ((const float4*)bvec)[threadIdx.x];
    ushort4 o4;
    o4.x = f2bf((v.x - mu) * rs * gv.x + bv.x);
    o4.y = f2bf((v.y - mu) * rs * gv.y + bv.y);
    o4.z = f2bf((v.z - mu) * rs * gv.z + bv.z);
    o4.w = f2bf((v.w - mu) * rs * gv.w + bv.w);
    ((ushort4*)(out + (size_t)row * ND))[threadIdx.x] = o4;
}

// ---------------------------------------------------------------------------
// gemm8p: 256x256 tile, BK=64, 4 phases/tile, counted vmcnt(6) at q3.
// (FFN1 path — verified.)
// ---------------------------------------------------------------------------
template<bool HAS_BIAS, bool RELU, int RES_MODE, bool OUT_F32>
__global__ __launch_bounds__(512, 2)
void gemm8p(const ushort_t* __restrict__ A, const ushort_t* __restrict__ Bt,
            const float* __restrict__ bias, const void* __restrict__ res,
            void* __restrict__ outp, int M, int N, int K) {
    constexpr int BN = 256;
    constexpr int NFR = BN / 64;
    __shared__ __align__(16) ushort_t As[2][256 * 64];
    __shared__ __align__(16) ushort_t Bs[2][BN * 64];
    const int t = threadIdx.x;
    const int wave = t >> 6, lane = t & 63;
    const int wm = wave >> 2, wn = wave & 3;
    const int g = lane >> 4, l16 = lane & 15;
    int wid = blockIdx.y * gridDim.x + blockIdx.x;
    const int cpx = (gridDim.x * gridDim.y) >> 3;
    wid = (wid & 7) * cpx + (wid >> 3);
    const int m0 = (wid / gridDim.x) * 256;
    const int n0 = (wid % gridDim.x) * BN;
    const int lrow8 = lane >> 3;
    const int srcCol = ((lane & 7) ^ lrow8) * 8;
    const ushort_t* Abase = A + (size_t)m0 * K + srcCol;
    const ushort_t* Bbase = Bt + (size_t)n0 * K + srcCol;
    const int NKT = K >> 6;

    f32x4 acc[8][NFR] = {};

    auto stageAhalf = [&](int kt, int h, int slot) {
        #pragma unroll
        for (int j = 2 * h; j < 2 * h + 2; j++) {
            const int rowbase = j * 64 + wave * 8;
            async_load16(Abase + (size_t)(rowbase + lrow8) * K + kt * 64,
                         &As[slot][rowbase * 64]);
        }
    };
    auto stageBhalf = [&](int kt, int h, int slot) {
        #pragma unroll
        for (int j = 2 * h; j < 2 * h + 2; j++) {
            const int rowbase = j * 64 + wave * 8;
            async_load16(Bbase + (size_t)(rowbase + lrow8) * K + kt * 64,
                         &Bs[slot][rowbase * 64]);
        }
    };

    stageAhalf(0, 0, 0); stageAhalf(0, 1, 0);
    stageBhalf(0, 0, 0); stageBhalf(0, 1, 0);
    stageBhalf(1, 0, 1); stageBhalf(1, 1, 1);
    stageAhalf(1, 0, 1);
    asm volatile("s_waitcnt vmcnt(6)" ::: "memory");
    __builtin_amdgcn_s_barrier();
    __builtin_amdgcn_sched_barrier(0);

    for (int kt = 0; kt < NKT; ++kt) {
        const int cur = kt & 1, nxt = cur ^ 1;
        const ushort_t* as = As[cur];
        const ushort_t* bs = Bs[cur];
        bf16x8 bfr[NFR][2];
        #pragma unroll
        for (int q = 0; q < 4; q++) {
            if (q == 0) {
                #pragma unroll
                for (int nf = 0; nf < NFR; nf++)
                    #pragma unroll
                    for (int ks = 0; ks < 2; ks++) {
                        const int row = wn * (BN / 4) + nf * 16 + l16;
                        int a = row * 128 + ks * 64 + 16 * g;
                        a ^= (row & 7) << 4;
                        bfr[nf][ks] = *(const bf16x8*)((const char*)bs + a);
                    }
            }
            bf16x8 af[2][2];
            #pragma unroll
            for (int mi2 = 0; mi2 < 2; mi2++)
                #pragma unroll
                for (int ks = 0; ks < 2; ks++) {
                    const int row = q * 64 + wm * 32 + mi2 * 16 + l16;
                    int a = row * 128 + ks * 64 + 16 * g;
                    a ^= (row & 7) << 4;
                    af[mi2][ks] = *(const bf16x8*)((const char*)as + a);
                }
            if (q == 0)      { if (kt + 1 < NKT) stageAhalf(kt + 1, 1, nxt); }
            else if (q == 1) { if (kt + 2 < NKT) stageBhalf(kt + 2, 0, cur); }
            else if (q == 2) { if (kt + 2 < NKT) stageBhalf(kt + 2, 1, cur); }
            else             { if (kt + 2 < NKT) stageAhalf(kt + 2, 0, cur); }
            __builtin_amdgcn_sched_barrier(0);
            if (q == 3) {
                if (kt >= NKT - 2) asm volatile("s_waitcnt vmcnt(0)" ::: "memory");
                else               asm volatile("s_waitcnt vmcnt(6)" ::: "memory");
            }
            __builtin_amdgcn_s_barrier();
            __builtin_amdgcn_sched_barrier(0);
            __builtin_amdgcn_s_setprio(1);
            #pragma unroll
            for (int mi2 = 0; mi2 < 2; mi2++)
                #pragma unroll
                for (int nf = 0; nf < NFR; nf++)
                    #pragma unroll
                    for (int ks = 0; ks < 2; ks++)
                        acc[q * 2 + mi2][nf] = __builtin_amdgcn_mfma_f32_16x16x32_bf16(
                            af[mi2][ks], bfr[nf][ks], acc[q * 2 + mi2][nf], 0, 0, 0);
            __builtin_amdgcn_s_setprio(0);
            __builtin_amdgcn_s_barrier();
            __builtin_amdgcn_sched_barrier(0);
        }
    }

    const int gc0 = n0 + wn * (BN / 4) + l16;
    #pragma unroll
    for (int mi = 0; mi < 8; mi++) {
        const int rowb = m0 + (mi >> 1) * 64 + wm * 32 + (mi & 1) * 16 + g * 4;
        #pragma unroll
        for (int nf = 0; nf < NFR; nf++) {
            const int col = gc0 + nf * 16;
            float bb = 0.f;
            if constexpr (HAS_BIAS) bb = bias[col];
            #pragma unroll
            for (int r = 0; r < 4; r++) {
                const int row = rowb + r;
                float v = acc[mi][nf][r] + bb;
                if constexpr (RELU) v = fmaxf(v, 0.f);
                if constexpr (RES_MODE == 1)
                    v += ((const float*)res)[(size_t)row * N + col];
                else if constexpr (RES_MODE == 2)
                    v += bf2f(((const ushort_t*)res)[(size_t)row * N + col]);
                if constexpr (OUT_F32)
                    ((float*)outp)[(size_t)row * N + col] = v;
                else
                    ((ushort_t*)outp)[(size_t)row * N + col] = f2bf(v);
            }
        }
    }
}

// ---------------------------------------------------------------------------
// gemm2b64: 128x128 tile, BK=64, 2 blocks/CU cross-block overlap (round-15
// verified). Counted vmcnt(8); (row&7)<<4 swizzle; 0 conflicts.
// OUT_MODE: 0 normal; 1 qkv-split (n0>=2048 -> V transposed into vTp).
// ---------------------------------------------------------------------------
template<bool HAS_BIAS, bool RELU, int RES_MODE, bool OUT_F32, int OUT_MODE = 0>
__global__ __launch_bounds__(256, 2)
void gemm2b64(const ushort_t* __restrict__ A, const ushort_t* __restrict__ Bt,
              const float* __restrict__ bias, const void* __restrict__ res,
              void* __restrict__ outp, ushort_t* __restrict__ vTp,
              int M, int N, int K) {
    __shared__ __align__(16) ushort_t As[2][128 * 64];
    __shared__ __align__(16) ushort_t Bs[2][128 * 64];
    const int t = threadIdx.x;
    const int wave = t >> 6, lane = t & 63;
    const int wm = wave >> 1, wn = wave & 1;        // 2M x 2N
    const int g = lane >> 4, l16 = lane & 15;
    int wid = blockIdx.y * gridDim.x + blockIdx.x;
    const int cpx = (gridDim.x * gridDim.y) >> 3;
    wid = (wid & 7) * cpx + (wid >> 3);
    const int m0 = (wid / gridDim.x) * 128;
    const int n0 = (wid % gridDim.x) * 128;
    const int rw = lane >> 3, ck = lane & 7;        // 8 rows x 8 chunks of 16B
    const int srcCol = (ck ^ rw) * 8;               // pre-swizzled source (ushorts)
    const ushort_t* Abase = A + (size_t)m0 * K + srcCol;
    const ushort_t* Bbase = Bt + (size_t)n0 * K + srcCol;
    const int NKT = K >> 6;

    f32x4 acc[4][4] = {};   // [mi][nf]

    auto stage = [&](int kt, int slot) {
        #pragma unroll
        for (int j = 0; j < 4; j++) {
            const int rowbase = j * 32 + wave * 8;  // wave-uniform
            async_load16(Abase + (size_t)(rowbase + rw) * K + kt * 64,
                         &As[slot][rowbase * 64]);
        }
        #pragma unroll
        for (int j = 0; j < 4; j++) {
            const int rowbase = j * 32 + wave * 8;
            async_load16(Bbase + (size_t)(rowbase + rw) * K + kt * 64,
                         &Bs[slot][rowbase * 64]);
        }
    };

    stage(0, 0);
    stage(1, 1);

    for (int kt = 0; kt < NKT; ++kt) {
        const int cur = kt & 1;
        if (kt >= NKT - 1) asm volatile("s_waitcnt vmcnt(0)" ::: "memory");
        else               asm volatile("s_waitcnt vmcnt(8)" ::: "memory");
        __builtin_amdgcn_s_barrier();
        __builtin_amdgcn_sched_barrier(0);

        const ushort_t* as = As[cur];
        const ushort_t* bs = Bs[cur];
        bf16x8 af[4][2], bfr[4][2];
        #pragma unroll
        for (int mi = 0; mi < 4; mi++)
            #pragma unroll
            for (int ks = 0; ks < 2; ks++) {
                const int row = wm * 64 + mi * 16 + l16;
                int a = row * 128 + ks * 64 + 16 * g;
                a ^= (row & 7) << 4;
                af[mi][ks] = *(const bf16x8*)((const char*)as + a);
            }
        #pragma unroll
        for (int nf = 0; nf < 4; nf++)
            #pragma unroll
            for (int ks = 0; ks < 2; ks++) {
                const int row = wn * 64 + nf * 16 + l16;
                int a = row * 128 + ks * 64 + 16 * g;
                a ^= (row & 7) << 4;
                bfr[nf][ks] = *(const bf16x8*)((const char*)bs + a);
            }
        __builtin_amdgcn_s_setprio(1);
        #pragma unroll
        for (int mi = 0; mi < 4; mi++)
            #pragma unroll
            for (int nf = 0; nf < 4; nf++)
                #pragma unroll
                for (int ks = 0; ks < 2; ks++)
                    acc[mi][nf] = __builtin_amdgcn_mfma_f32_16x16x32_bf16(
                        af[mi][ks], bfr[nf][ks], acc[mi][nf], 0, 0, 0);
        __builtin_amdgcn_s_setprio(0);
        __builtin_amdgcn_s_barrier();
        __builtin_amdgcn_sched_barrier(0);
        if (kt + 2 < NKT) stage(kt + 2, cur);
    }

    const int gc0 = n0 + wn * 64 + l16;
    if constexpr (OUT_MODE == 1) {
        if (n0 >= 2048) {
            // V -> transposed store: vT[b*1024 + (col-2048)][t], 4 t's per store
            #pragma unroll
            for (int mi = 0; mi < 4; mi++) {
                const int rowb = m0 + wm * 64 + mi * 16 + g * 4;
                const int b = rowb >> 11, tt = rowb & 2047;
                #pragma unroll
                for (int nf = 0; nf < 4; nf++) {
                    const int col = gc0 + nf * 16;
                    ushort4 o4;
                    o4.x = f2bf(acc[mi][nf][0]);
                    o4.y = f2bf(acc[mi][nf][1]);
                    o4.z = f2bf(acc[mi][nf][2]);
                    o4.w = f2bf(acc[mi][nf][3]);
                    *(ushort4*)(vTp + (size_t)(b * 1024 + col - 2048) * NT + tt) = o4;
                }
            }
            return;
        }
    }
    #pragma unroll
    for (int mi = 0; mi < 4; mi++) {
        const int rowb = m0 + wm * 64 + mi * 16 + g * 4;
        #pragma unroll
        for (int nf = 0; nf < 4; nf++) {
            const int col = gc0 + nf * 16;
            float bb = 0.f;
            if constexpr (HAS_BIAS) bb = bias[col];
            #pragma unroll
            for (int r = 0; r < 4; r++) {
                const int row = rowb + r;
                float v = acc[mi][nf][r] + bb;
                if constexpr (RELU) v = fmaxf(v, 0.f);
                if constexpr (RES_MODE == 1)
                    v += ((const float*)res)[(size_t)row * N + col];
                else if constexpr (RES_MODE == 2)
                    v += bf2f(((const ushort_t*)res)[(size_t)row * N + col]);
                if constexpr (OUT_F32)
                    ((float*)outp)[(size_t)row * N + col] = v;
                else
                    ((ushort_t*)outp)[(size_t)row * N + col] = f2bf(v);
            }
        }
    }
}

// ---------------------------------------------------------------------------
// Causal flash attention, no max-tracking; row-sum via ones-MFMA. V arrives
// pre-transposed (vT) and is staged like K via global_load_lds (source
// pre-swizzled by c(d)=(d&7)^(d>>3)). Pw vectorized (36-word rows).
// Grid (16,64) = 1024 SINGLE-q-tile blocks (ungrouped pairs): LDS 50KB ->
// 3 blocks/CU resident = 12 waves/CU (was 8). Blocks dispatched LONGEST-
// FIRST (qt = 15 - rank) so the 32-iter blocks start in round one; 8 bh
// share an XCD for KV L2 locality. Kernel body unchanged.
// ---------------------------------------------------------------------------
__global__ __launch_bounds__(256)
void attn_kernel(const ushort_t* __restrict__ qkv, const ushort_t* __restrict__ vT,
                 ushort_t* __restrict__ out) {
    __shared__ __align__(16) ushort_t Ks[2][64 * 64];  // linear, XOR-swizzle on read
    __shared__ __align__(16) ushort_t Vt[2][64 * 64];  // d-major, XOR-swizzled
    __shared__ __align__(16) unsigned int Pw[4][32][36];  // per-wave P words
    const int L = blockIdx.y * gridDim.x + blockIdx.x; // grid (16,64) -> 1024
    const int xcd = L & 7, kk = L >> 3;                // kk 0..127 per XCD
    const int bh = ((kk & 7) << 3) | xcd;              // 8 bh share an XCD
    const int qt = 15 - (kk >> 3);                     // longest-first dispatch
    const int b = bh >> 4, h = bh & 15;
    const int t = threadIdx.x, wave = t >> 6, lane = t & 63;
    const int g = lane >> 4, q16 = lane & 15;
    const size_t base = ((size_t)b * NT) * 3072 + h * NHD;
    const ushort_t* qp_base = qkv + base;
    const ushort_t* kb = qkv + base + 1024;
    const ushort_t* vbt = vT + (size_t)bh * 64 * NT;   // rows d, length NT
    const int krw = lane >> 3, kck = lane & 7;
    const int ksrc = (kck ^ krw) * 8;                  // pre-swizzled source column

    bf16x8 ones_f;
    {
        uint4 u = {0x3F803F80u, 0x3F803F80u, 0x3F803F80u, 0x3F803F80u};
        ones_f = __builtin_bit_cast(bf16x8, u);
    }

    auto stageK = [&](int kv, int buf) {
        #pragma unroll
        for (int c = 0; c < 2; c++) {
            const int rowbase = c * 32 + wave * 8;     // wave-uniform
            async_load16(kb + (size_t)(kv * 64 + rowbase + krw) * 3072 + ksrc,
                         &Ks[buf][rowbase * 64]);
        }
    };
    auto stageV = [&](int kv, int buf) {
        #pragma unroll
        for (int c = 0; c < 2; c++) {
            const int rowbase = c * 32 + wave * 8;     // wave-uniform
            const int scol = ((kck ^ krw ^ ((c * 4 + wave) & 7)) * 8);
            async_load16(vbt + (size_t)(rowbase + krw) * NT + kv * 64 + scol,
                         &Vt[buf][rowbase * 64]);
        }
    };

    const int q0 = qt * 128;
    const int wq0 = q0 + wave * 32;
    bf16x8 qf[2][2];
    #pragma unroll
    for (int qb2 = 0; qb2 < 2; qb2++) {
        const ushort_t* qp = qp_base + (size_t)(wq0 + 16 * qb2 + q16) * 3072 + 8 * g;
        qf[qb2][0] = *(const bf16x8*)qp;
        qf[qb2][1] = *(const bf16x8*)(qp + 32);
    }
    f32x4 of[2][4] = {};
    f32x4 of4[2] = {};               // row-sum accumulator (l), via ones-MFMA
    const int nkv = 2 * qt + 2;

    stageK(0, 0);
    stageV(0, 0);
    __syncthreads();                 // drains vmcnt before first use

    for (int kv = 0; kv < nkv; ++kv) {
        const int cur = kv & 1, nxt = cur ^ 1;
        if (kv + 1 < nkv) {
            stageK(kv + 1, nxt);
            stageV(kv + 1, nxt);
        }
        __builtin_amdgcn_sched_barrier(0);   // pin prefetch issue before compute

        const int kbase = kv * 64;
        if (kbase <= wq0 + 31) {
            bf16x8 kf[4][2];
            #pragma unroll
            for (int n = 0; n < 4; n++)
                #pragma unroll
                for (int kd = 0; kd < 2; kd++) {
                    int row = n * 16 + q16;
                    int a = row * 128 + (kd * 64 + 16 * g);
                    a ^= ((row & 7) << 4);
                    kf[n][kd] = *(const bf16x8*)((const char*)&Ks[cur][0] + a);
                }

            f32x4 sf[2][4] = {};
            #pragma unroll
            for (int n = 0; n < 4; n++)
                #pragma unroll
                for (int kd = 0; kd < 2; kd++) {
                    sf[0][n] = __builtin_amdgcn_mfma_f32_16x16x32_bf16(
                        kf[n][kd], qf[0][kd], sf[0][n], 0, 0, 0);
                    sf[1][n] = __builtin_amdgcn_mfma_f32_16x16x32_bf16(
                        kf[n][kd], qf[1][kd], sf[1][n], 0, 0, 0);
                }

            #pragma unroll
            for (int qb2 = 0; qb2 < 2; qb2++) {
                const int wqb = wq0 + 16 * qb2 + q16;
                const bool partial = (kbase + 63 > wq0 + 16 * qb2);
                float p[4][4];
                #pragma unroll
                for (int n = 0; n < 4; n++)
                    #pragma unroll
                    for (int r = 0; r < 4; r++) {
                        float v = sf[qb2][n][r];
                        if (partial) {
                            int kg = kbase + n * 16 + 4 * g + r;
                            if (kg > wqb) v = -1.0e30f;   // exp2 -> 0
                        }
                        p[n][r] = exp2_fast(v);
                    }
                unsigned int* pr = &Pw[wave][16 * qb2 + q16][0];
                #pragma unroll
                for (int n = 0; n < 4; n++) {
                    uint2 wv;
                    wv.x = cvt_pk_bf16(p[n][0], p[n][1]);
                    wv.y = cvt_pk_bf16(p[n][2], p[n][3]);
                    *(uint2*)(pr + 8 * n + 2 * g) = wv;   // 8B-aligned
                }
            }

            #pragma unroll
            for (int kbk = 0; kbk < 2; kbk++) {
                bf16x8 pfr[2];
                #pragma unroll
                for (int qb2 = 0; qb2 < 2; qb2++) {
                    const unsigned int* pr = &Pw[wave][16 * qb2 + q16][0];
                    uint4 pu = *(const uint4*)(pr + 16 * kbk + 4 * g);  // 16B-aligned
                    pfr[qb2] = __builtin_bit_cast(bf16x8, pu);
                }
                of4[0] = __builtin_amdgcn_mfma_f32_16x16x32_bf16(
                    ones_f, pfr[0], of4[0], 0, 0, 0);
                of4[1] = __builtin_amdgcn_mfma_f32_16x16x32_bf16(
                    ones_f, pfr[1], of4[1], 0, 0, 0);
                #pragma unroll
                for (int nf = 0; nf < 4; nf++) {
                    const int d = nf * 16 + q16;
                    int a = (d << 7) + (kbk * 64 + 16 * g);
                    a ^= (((d & 7) ^ ((d >> 3) & 7)) << 4);
                    bf16x8 vf = *(const bf16x8*)((const char*)&Vt[cur][0] + a);
                    of[0][nf] = __builtin_amdgcn_mfma_f32_16x16x32_bf16(
                        vf, pfr[0], of[0][nf], 0, 0, 0);
                    of[1][nf] = __builtin_amdgcn_mfma_f32_16x16x32_bf16(
                        vf, pfr[1], of[1][nf], 0, 0, 0);
                }
            }
        }

        __syncthreads();   // drains K+V prefetch + buffer handoff
    }

    #pragma unroll
    for (int qb2 = 0; qb2 < 2; qb2++) {
        float rl = 1.f / of4[qb2][0];
        const size_t orow = (size_t)b * NT + q0 + wave * 32 + 16 * qb2 + q16;
        #pragma unroll
        for (int nf = 0; nf < 4; nf++) {
            ushort4 o4;
            o4.x = f2bf(of[qb2][nf][0] * rl);
            o4.y = f2bf(of[qb2][nf][1] * rl);
            o4.z = f2bf(of[qb2][nf][2] * rl);
            o4.w = f2bf(of[qb2][nf][3] * rl);
            *(ushort4*)(out + orow * ND + h * NHD + nf * 16 + 4 * g) = o4;
        }
    }
}

// ---------------------------------------------------------------------------
extern "C" void kernel_launch(void* const* d_in, const int* in_sizes, int n_in,
                              void* d_out, int out_size, void* d_ws, size_t ws_size,
                              hipStream_t stream) {
    const float* x     = (const float*)d_in[0];
    const float* ln1_g = (const float*)d_in[1];
    const float* ln1_b = (const float*)d_in[2];
    const float* ln2_g = (const float*)d_in[3];
    const float* ln2_b = (const float*)d_in[4];
    const float* Wq    = (const float*)d_in[5];
    const float* Wk    = (const float*)d_in[6];
    const float* Wv    = (const float*)d_in[7];
    const float* Wo    = (const float*)d_in[8];
    const float* bo    = (const float*)d_in[9];
    const float* W1    = (const float*)d_in[10];
    const float* b1    = (const float*)d_in[11];
    const float* W2    = (const float*)d_in[12];
    const float* b2    = (const float*)d_in[13];
    float* outp = (float*)d_out;

    char* w = (char*)d_ws;
    ushort_t* Wqkv_t = (ushort_t*)(w);                    // 6 MiB  (3072x1024)
    ushort_t* Wo_t   = (ushort_t*)(w + 6291456);          // 2 MiB  (1024x1024)
    ushort_t* W1_t   = (ushort_t*)(w + 8388608);          // 8 MiB  (4096x1024)
    ushort_t* W2_t   = (ushort_t*)(w + 16777216);         // 8 MiB  (1024x4096)
    ushort_t* xn     = (ushort_t*)(w + 25165824);         // 16 MiB (8192x1024), also hn
    ushort_t* qkv    = (ushort_t*)(w + 41943040);         // 48 MiB (8192x3072; V third unused)
    ushort_t* attn_o = qkv + (size_t)MTOK * 3072;         // 16 MiB (8192x1024)
    ushort_t* ff1    = qkv;                               // 64 MiB (8192x4096) reuse
    ushort_t* hbuf   = (ushort_t*)(w + 41943040 + 67108864);      // 16 MiB (bf16)
    ushort_t* vT     = (ushort_t*)(w + 41943040 + 67108864 + 16777216); // 16 MiB (4096x2048)

    dim3 tb(32, 8);
    transpose_qkv_to_bf16<<<dim3(2, 32, 48), tb, 0, stream>>>(Wq, Wk, Wv, Wqkv_t);
    transpose_to_bf16<<<dim3(32, 32), tb, 0, stream>>>(Wo, Wo_t, 1024, 1024);
    transpose_to_bf16<<<dim3(128, 32), tb, 0, stream>>>(W1, W1_t, 1024, 4096);
    transpose_to_bf16<<<dim3(32, 128), tb, 0, stream>>>(W2, W2_t, 4096, 1024);

    layernorm_to_bf16<<<MTOK, 256, 0, stream>>>(x, ln1_g, ln1_b, xn);

    // QKV via gemm2b64 (2 blocks/CU overlap): Q,K row-major; V -> vT transposed
    gemm2b64<false, false, 0, false, 1><<<dim3(24, 64), 256, 0, stream>>>(
        xn, Wqkv_t, nullptr, nullptr, qkv, vT, MTOK, 3072, 1024);

    attn_kernel<<<dim3(16, 64), 256, 0, stream>>>(qkv, vT, attn_o);

    // Wo via gemm2b64: h = attn@Wo + bo + x (bf16 out)
    gemm2b64<true, false, 1, false><<<dim3(8, 64), 256, 0, stream>>>(
        attn_o, Wo_t, bo, x, hbuf, nullptr, MTOK, 1024, 1024);

    layernorm_bf16<<<MTOK, 256, 0, stream>>>(hbuf, ln2_g, ln2_b, xn);

    // FFN1: 256x256 gemm8p
    gemm8p<true, true, 0, false><<<dim3(16, 32), 512, 0, stream>>>(
        xn, W1_t, b1, nullptr, ff1, MTOK, NF, 1024);

    // FFN2: N=1024, K=4096 -> gemm2b64
    gemm2b64<true, false, 2, true><<<dim3(8, 64), 256, 0, stream>>>(
        ff1, W2_t, b2, hbuf, outp, nullptr, MTOK, 1024, NF);
}

// Round 21
// 338.796 us; speedup vs baseline: 1.0182x; 1.0080x over previous
//
#include <hip/hip_runtime.h>
#include <hip/hip_bf16.h>

#define NB 4
#define NT 2048
#define ND 1024
#define NH 16
#define NHD 64
#define NF 4096
#define MTOK (NB*NT)  // 8192

typedef float f32x4 __attribute__((ext_vector_type(4)));
typedef __bf16 bf16x8 __attribute__((ext_vector_type(8)));
typedef short s16x8 __attribute__((ext_vector_type(8)));
typedef unsigned short ushort_t;

__device__ inline ushort_t f2bf(float f) {
    unsigned int u = __builtin_bit_cast(unsigned int, f);
    unsigned int r = (u + 0x7FFFu + ((u >> 16) & 1u)) >> 16;
    return (ushort_t)r;
}
__device__ inline float bf2f(ushort_t u) {
    return __builtin_bit_cast(float, (unsigned int)u << 16);
}

__device__ __forceinline__ void async_load16(const void* g, void* l) {
    __builtin_amdgcn_global_load_lds(
        (const __attribute__((address_space(1))) void*)g,
        (__attribute__((address_space(3))) void*)l, 16, 0, 0);
}

__device__ __forceinline__ unsigned int cvt_pk_bf16(float lo, float hi) {
    unsigned int r;
    asm("v_cvt_pk_bf16_f32 %0, %1, %2" : "=v"(r) : "v"(lo), "v"(hi));
    return r;
}

__device__ __forceinline__ float exp2_fast(float x) {
    float r;
    asm("v_exp_f32 %0, %1" : "=v"(r) : "v"(x));
    return r;
}

// ---------------------------------------------------------------------------
// Transpose-convert: src fp32 (R x C) row-major -> dst bf16 (C x R) row-major
// ---------------------------------------------------------------------------
__global__ __launch_bounds__(256)
void transpose_to_bf16(const float* __restrict__ src, ushort_t* __restrict__ dst,
                       int R, int C) {
    __shared__ float tile[32][33];
    int c0 = blockIdx.x * 32, r0 = blockIdx.y * 32;
    #pragma unroll
    for (int i = 0; i < 32; i += 8)
        tile[threadIdx.y + i][threadIdx.x] =
            src[(size_t)(r0 + threadIdx.y + i) * C + c0 + threadIdx.x];
    __syncthreads();
    #pragma unroll
    for (int i = 0; i < 32; i += 8)
        dst[(size_t)(c0 + threadIdx.y + i) * R + r0 + threadIdx.x] =
            f2bf(tile[threadIdx.x][threadIdx.y + i]);
}

// QKV weights: Wq/Wk/Wv are (H, D, HD). Build Bt (3072 x 1024) bf16.
// Wq pre-scaled by (1/32)*log2(e): QK^T scores come out in exp2 domain.
__global__ __launch_bounds__(256)
void transpose_qkv_to_bf16(const float* __restrict__ Wq, const float* __restrict__ Wk,
                           const float* __restrict__ Wv, ushort_t* __restrict__ dst) {
    __shared__ float tile[32][33];
    int z = blockIdx.z;            // 0..47
    int w = z >> 4, h = z & 15;
    const float* src = (w == 0 ? Wq : (w == 1 ? Wk : Wv)) + (size_t)h * ND * NHD;
    const float sc = (w == 0) ? 0.03125f * 1.44269504f : 1.0f;
    ushort_t* out = dst + ((size_t)w * ND + h * NHD) * ND;
    int c0 = blockIdx.x * 32, r0 = blockIdx.y * 32;
    #pragma unroll
    for (int i = 0; i < 32; i += 8)
        tile[threadIdx.y + i][threadIdx.x] =
            src[(size_t)(r0 + threadIdx.y + i) * NHD + c0 + threadIdx.x];
    __syncthreads();
    #pragma unroll
    for (int i = 0; i < 32; i += 8)
        out[(size_t)(c0 + threadIdx.y + i) * ND + r0 + threadIdx.x] =
            f2bf(tile[threadIdx.x][threadIdx.y + i] * sc);
}

// ---------------------------------------------------------------------------
// LayerNorm (rows of 1024 fp32) -> bf16 out
// ---------------------------------------------------------------------------
__global__ __launch_bounds__(256)
void layernorm_to_bf16(const float* __restrict__ x, const float* __restrict__ g,
                       const float* __restrict__ bvec, ushort_t* __restrict__ out) {
    int row = blockIdx.x;
    const float4* xr = (const float4*)(x + (size_t)row * ND);
    float4 v = xr[threadIdx.x];
    float s = v.x + v.y + v.z + v.w;
    float s2 = v.x * v.x + v.y * v.y + v.z * v.z + v.w * v.w;
    #pragma unroll
    for (int o = 32; o >= 1; o >>= 1) {
        s += __shfl_xor(s, o);
        s2 += __shfl_xor(s2, o);
    }
    __shared__ float red[8];
    int wave = threadIdx.x >> 6, lane = threadIdx.x & 63;
    if (lane == 0) { red[wave] = s; red[4 + wave] = s2; }
    __syncthreads();
    float ts = red[0] + red[1] + red[2] + red[3];
    float ts2 = red[4] + red[5] + red[6] + red[7];
    float mu = ts * (1.f / ND);
    float var = ts2 * (1.f / ND) - mu * mu;
    float rs = rsqrtf(var + 1e-5f);
    float4 gv = ((const float4*)g)[threadIdx.x];
    float4 bv = ((const float4*)bvec)[threadIdx.x];
    ushort4 o4;
    o4.x = f2bf((v.x - mu) * rs * gv.x + bv.x);
    o4.y = f2bf((v.y - mu) * rs * gv.y + bv.y);
    o4.z = f2bf((v.z - mu) * rs * gv.z + bv.z);
    o4.w = f2bf((v.w - mu) * rs * gv.w + bv.w);
    ((ushort4*)(out + (size_t)row * ND))[threadIdx.x] = o4;
}

// LayerNorm on bf16 input (rows of 1024) -> bf16 out
__global__ __launch_bounds__(256)
void layernorm_bf16(const ushort_t* __restrict__ x, const float* __restrict__ g,
                    const float* __restrict__ bvec, ushort_t* __restrict__ out) {
    int row = blockIdx.x;
    ushort4 u4 = ((const ushort4*)(x + (size_t)row * ND))[threadIdx.x];
    float4 v;
    v.x = bf2f(u4.x); v.y = bf2f(u4.y); v.z = bf2f(u4.z); v.w = bf2f(u4.w);
    float s = v.x + v.y + v.z + v.w;
    float s2 = v.x * v.x + v.y * v.y + v.z * v.z + v.w * v.w;
    #pragma unroll
    for (int o = 32; o >= 1; o >>= 1) {
        s += __shfl_xor(s, o);
        s2 += __shfl_xor(s2, o);
    }
    __shared__ float red[8];
    int wave = threadIdx.x >> 6, lane = threadIdx.x & 63;
    if (lane == 0) { red[wave] = s; red[4 + wave] = s2; }
    __syncthreads();
    float ts = red[0] + red[1] + red[2] + red[3];
    float ts2 = red[4] + red[5] + red[6] + red[7];
    float mu = ts * (1.f / ND);
    float var = ts2 * (1.f / ND) - mu * mu;
    float rs = rsqrtf(var + 1e-5f);
    float4 gv = ((const float4*)g)[threadIdx.x];
    float4 bv = ((const float4*)bvec)[threadIdx.x];
    ushort4 o4;
    o4.x = f2bf((v.x - mu) * rs * gv.x + bv.x);
    o4.y = f2bf((v.y - mu) * rs * gv.y + bv.y);
    o4.z = f2bf((v.z - mu) * rs * gv.z + bv.z);
    o4.w = f2bf((v.w - mu) * rs * gv.w + bv.w);
    ((ushort4*)(out + (size_t)row * ND))[threadIdx.x] = o4;
}

// ---------------------------------------------------------------------------
// gemm8p: 256x256 tile, BK=64, 4 phases/tile, counted vmcnt(6) at q3.
// (FFN1 path — verified.)
// ---------------------------------------------------------------------------
template<bool HAS_BIAS, bool RELU, int RES_MODE, bool OUT_F32>
__global__ __launch_bounds__(512, 2)
void gemm8p(const ushort_t* __restrict__ A, const ushort_t* __restrict__ Bt,
            const float* __restrict__ bias, const void* __restrict__ res,
            void* __restrict__ outp, int M, int N, int K) {
    constexpr int BN = 256;
    constexpr int NFR = BN / 64;
    __shared__ __align__(16) ushort_t As[2][256 * 64];
    __shared__ __align__(16) ushort_t Bs[2][BN * 64];
    const int t = threadIdx.x;
    const int wave = t >> 6, lane = t & 63;
    const int wm = wave >> 2, wn = wave & 3;
    const int g = lane >> 4, l16 = lane & 15;
    int wid = blockIdx.y * gridDim.x + blockIdx.x;
    const int cpx = (gridDim.x * gridDim.y) >> 3;
    wid = (wid & 7) * cpx + (wid >> 3);
    const int m0 = (wid / gridDim.x) * 256;
    const int n0 = (wid % gridDim.x) * BN;
    const int lrow8 = lane >> 3;
    const int srcCol = ((lane & 7) ^ lrow8) * 8;
    const ushort_t* Abase = A + (size_t)m0 * K + srcCol;
    const ushort_t* Bbase = Bt + (size_t)n0 * K + srcCol;
    const int NKT = K >> 6;

    f32x4 acc[8][NFR] = {};

    auto stageAhalf = [&](int kt, int h, int slot) {
        #pragma unroll
        for (int j = 2 * h; j < 2 * h + 2; j++) {
            const int rowbase = j * 64 + wave * 8;
            async_load16(Abase + (size_t)(rowbase + lrow8) * K + kt * 64,
                         &As[slot][rowbase * 64]);
        }
    };
    auto stageBhalf = [&](int kt, int h, int slot) {
        #pragma unroll
        for (int j = 2 * h; j < 2 * h + 2; j++) {
            const int rowbase = j * 64 + wave * 8;
            async_load16(Bbase + (size_t)(rowbase + lrow8) * K + kt * 64,
                         &Bs[slot][rowbase * 64]);
        }
    };

    stageAhalf(0, 0, 0); stageAhalf(0, 1, 0);
    stageBhalf(0, 0, 0); stageBhalf(0, 1, 0);
    stageBhalf(1, 0, 1); stageBhalf(1, 1, 1);
    stageAhalf(1, 0, 1);
    asm volatile("s_waitcnt vmcnt(6)" ::: "memory");
    __builtin_amdgcn_s_barrier();
    __builtin_amdgcn_sched_barrier(0);

    for (int kt = 0; kt < NKT; ++kt) {
        const int cur = kt & 1, nxt = cur ^ 1;
        const ushort_t* as = As[cur];
        const ushort_t* bs = Bs[cur];
        bf16x8 bfr[NFR][2];
        #pragma unroll
        for (int q = 0; q < 4; q++) {
            if (q == 0) {
                #pragma unroll
                for (int nf = 0; nf < NFR; nf++)
                    #pragma unroll
                    for (int ks = 0; ks < 2; ks++) {
                        const int row = wn * (BN / 4) + nf * 16 + l16;
                        int a = row * 128 + ks * 64 + 16 * g;
                        a ^= (row & 7) << 4;
                        bfr[nf][ks] = *(const bf16x8*)((const char*)bs + a);
                    }
            }
            bf16x8 af[2][2];
            #pragma unroll
            for (int mi2 = 0; mi2 < 2; mi2++)
                #pragma unroll
                for (int ks = 0; ks < 2; ks++) {
                    const int row = q * 64 + wm * 32 + mi2 * 16 + l16;
                    int a = row * 128 + ks * 64 + 16 * g;
                    a ^= (row & 7) << 4;
                    af[mi2][ks] = *(const bf16x8*)((const char*)as + a);
                }
            if (q == 0)      { if (kt + 1 < NKT) stageAhalf(kt + 1, 1, nxt); }
            else if (q == 1) { if (kt + 2 < NKT) stageBhalf(kt + 2, 0, cur); }
            else if (q == 2) { if (kt + 2 < NKT) stageBhalf(kt + 2, 1, cur); }
            else             { if (kt + 2 < NKT) stageAhalf(kt + 2, 0, cur); }
            __builtin_amdgcn_sched_barrier(0);
            if (q == 3) {
                if (kt >= NKT - 2) asm volatile("s_waitcnt vmcnt(0)" ::: "memory");
                else               asm volatile("s_waitcnt vmcnt(6)" ::: "memory");
            }
            __builtin_amdgcn_s_barrier();
            __builtin_amdgcn_sched_barrier(0);
            __builtin_amdgcn_s_setprio(1);
            #pragma unroll
            for (int mi2 = 0; mi2 < 2; mi2++)
                #pragma unroll
                for (int nf = 0; nf < NFR; nf++)
                    #pragma unroll
                    for (int ks = 0; ks < 2; ks++)
                        acc[q * 2 + mi2][nf] = __builtin_amdgcn_mfma_f32_16x16x32_bf16(
                            af[mi2][ks], bfr[nf][ks], acc[q * 2 + mi2][nf], 0, 0, 0);
            __builtin_amdgcn_s_setprio(0);
            __builtin_amdgcn_s_barrier();
            __builtin_amdgcn_sched_barrier(0);
        }
    }

    const int gc0 = n0 + wn * (BN / 4) + l16;
    #pragma unroll
    for (int mi = 0; mi < 8; mi++) {
        const int rowb = m0 + (mi >> 1) * 64 + wm * 32 + (mi & 1) * 16 + g * 4;
        #pragma unroll
        for (int nf = 0; nf < NFR; nf++) {
            const int col = gc0 + nf * 16;
            float bb = 0.f;
            if constexpr (HAS_BIAS) bb = bias[col];
            #pragma unroll
            for (int r = 0; r < 4; r++) {
                const int row = rowb + r;
                float v = acc[mi][nf][r] + bb;
                if constexpr (RELU) v = fmaxf(v, 0.f);
                if constexpr (RES_MODE == 1)
                    v += ((const float*)res)[(size_t)row * N + col];
                else if constexpr (RES_MODE == 2)
                    v += bf2f(((const ushort_t*)res)[(size_t)row * N + col]);
                if constexpr (OUT_F32)
                    ((float*)outp)[(size_t)row * N + col] = v;
                else
                    ((ushort_t*)outp)[(size_t)row * N + col] = f2bf(v);
            }
        }
    }
}

// ---------------------------------------------------------------------------
// gemm2b64: 128x128 tile, BK=64, 2 blocks/CU cross-block overlap (round-15
// verified). Counted vmcnt(8); (row&7)<<4 swizzle; 0 conflicts.
// OUT_MODE: 0 normal; 1 qkv-split (n0>=2048 -> V transposed into vTp).
// ---------------------------------------------------------------------------
template<bool HAS_BIAS, bool RELU, int RES_MODE, bool OUT_F32, int OUT_MODE = 0>
__global__ __launch_bounds__(256, 2)
void gemm2b64(const ushort_t* __restrict__ A, const ushort_t* __restrict__ Bt,
              const float* __restrict__ bias, const void* __restrict__ res,
              void* __restrict__ outp, ushort_t* __restrict__ vTp,
              int M, int N, int K) {
    __shared__ __align__(16) ushort_t As[2][128 * 64];
    __shared__ __align__(16) ushort_t Bs[2][128 * 64];
    const int t = threadIdx.x;
    const int wave = t >> 6, lane = t & 63;
    const int wm = wave >> 1, wn = wave & 1;        // 2M x 2N
    const int g = lane >> 4, l16 = lane & 15;
    int wid = blockIdx.y * gridDim.x + blockIdx.x;
    const int cpx = (gridDim.x * gridDim.y) >> 3;
    wid = (wid & 7) * cpx + (wid >> 3);
    const int m0 = (wid / gridDim.x) * 128;
    const int n0 = (wid % gridDim.x) * 128;
    const int rw = lane >> 3, ck = lane & 7;        // 8 rows x 8 chunks of 16B
    const int srcCol = (ck ^ rw) * 8;               // pre-swizzled source (ushorts)
    const ushort_t* Abase = A + (size_t)m0 * K + srcCol;
    const ushort_t* Bbase = Bt + (size_t)n0 * K + srcCol;
    const int NKT = K >> 6;

    f32x4 acc[4][4] = {};   // [mi][nf]

    auto stage = [&](int kt, int slot) {
        #pragma unroll
        for (int j = 0; j < 4; j++) {
            const int rowbase = j * 32 + wave * 8;  // wave-uniform
            async_load16(Abase + (size_t)(rowbase + rw) * K + kt * 64,
                         &As[slot][rowbase * 64]);
        }
        #pragma unroll
        for (int j = 0; j < 4; j++) {
            const int rowbase = j * 32 + wave * 8;
            async_load16(Bbase + (size_t)(rowbase + rw) * K + kt * 64,
                         &Bs[slot][rowbase * 64]);
        }
    };

    stage(0, 0);
    stage(1, 1);

    for (int kt = 0; kt < NKT; ++kt) {
        const int cur = kt & 1;
        if (kt >= NKT - 1) asm volatile("s_waitcnt vmcnt(0)" ::: "memory");
        else               asm volatile("s_waitcnt vmcnt(8)" ::: "memory");
        __builtin_amdgcn_s_barrier();
        __builtin_amdgcn_sched_barrier(0);

        const ushort_t* as = As[cur];
        const ushort_t* bs = Bs[cur];
        bf16x8 af[4][2], bfr[4][2];
        #pragma unroll
        for (int mi = 0; mi < 4; mi++)
            #pragma unroll
            for (int ks = 0; ks < 2; ks++) {
                const int row = wm * 64 + mi * 16 + l16;
                int a = row * 128 + ks * 64 + 16 * g;
                a ^= (row & 7) << 4;
                af[mi][ks] = *(const bf16x8*)((const char*)as + a);
            }
        #pragma unroll
        for (int nf = 0; nf < 4; nf++)
            #pragma unroll
            for (int ks = 0; ks < 2; ks++) {
                const int row = wn * 64 + nf * 16 + l16;
                int a = row * 128 + ks * 64 + 16 * g;
                a ^= (row & 7) << 4;
                bfr[nf][ks] = *(const bf16x8*)((const char*)bs + a);
            }
        __builtin_amdgcn_s_setprio(1);
        #pragma unroll
        for (int mi = 0; mi < 4; mi++)
            #pragma unroll
            for (int nf = 0; nf < 4; nf++)
                #pragma unroll
                for (int ks = 0; ks < 2; ks++)
                    acc[mi][nf] = __builtin_amdgcn_mfma_f32_16x16x32_bf16(
                        af[mi][ks], bfr[nf][ks], acc[mi][nf], 0, 0, 0);
        __builtin_amdgcn_s_setprio(0);
        __builtin_amdgcn_s_barrier();
        __builtin_amdgcn_sched_barrier(0);
        if (kt + 2 < NKT) stage(kt + 2, cur);
    }

    const int gc0 = n0 + wn * 64 + l16;
    if constexpr (OUT_MODE == 1) {
        if (n0 >= 2048) {
            // V -> transposed store: vT[b*1024 + (col-2048)][t], 4 t's per store
            #pragma unroll
            for (int mi = 0; mi < 4; mi++) {
                const int rowb = m0 + wm * 64 + mi * 16 + g * 4;
                const int b = rowb >> 11, tt = rowb & 2047;
                #pragma unroll
                for (int nf = 0; nf < 4; nf++) {
                    const int col = gc0 + nf * 16;
                    ushort4 o4;
                    o4.x = f2bf(acc[mi][nf][0]);
                    o4.y = f2bf(acc[mi][nf][1]);
                    o4.z = f2bf(acc[mi][nf][2]);
                    o4.w = f2bf(acc[mi][nf][3]);
                    *(ushort4*)(vTp + (size_t)(b * 1024 + col - 2048) * NT + tt) = o4;
                }
            }
            return;
        }
    }
    #pragma unroll
    for (int mi = 0; mi < 4; mi++) {
        const int rowb = m0 + wm * 64 + mi * 16 + g * 4;
        #pragma unroll
        for (int nf = 0; nf < 4; nf++) {
            const int col = gc0 + nf * 16;
            float bb = 0.f;
            if constexpr (HAS_BIAS) bb = bias[col];
            #pragma unroll
            for (int r = 0; r < 4; r++) {
                const int row = rowb + r;
                float v = acc[mi][nf][r] + bb;
                if constexpr (RELU) v = fmaxf(v, 0.f);
                if constexpr (RES_MODE == 1)
                    v += ((const float*)res)[(size_t)row * N + col];
                else if constexpr (RES_MODE == 2)
                    v += bf2f(((const ushort_t*)res)[(size_t)row * N + col]);
                if constexpr (OUT_F32)
                    ((float*)outp)[(size_t)row * N + col] = v;
                else
                    ((ushort_t*)outp)[(size_t)row * N + col] = f2bf(v);
            }
        }
    }
}

// ---------------------------------------------------------------------------
// Causal flash attention, no max-tracking; row-sum via ones-MFMA. V arrives
// pre-transposed (vT); K/V staged via global_load_lds (one issue per thread
// per buffer; 512 threads cover the 64x64 tile). QBLK=256: 8 waves x 32
// q-rows (wave body identical to the verified 4-wave version). LDS 68KB ->
// 2 blocks/CU = 16 waves/CU; K/V traffic and barriers per q-row halved.
// 512 blocks = exactly 2/CU; block L and L+256 share (xcd,bh) with
// complementary qt (qt + qt' = 7) -> per-CU work balanced at 36 iters.
// Heavy set (qt>=4) dispatched first.
// ---------------------------------------------------------------------------
__global__ __launch_bounds__(512, 4)
void attn_kernel(const ushort_t* __restrict__ qkv, const ushort_t* __restrict__ vT,
                 ushort_t* __restrict__ out) {
    __shared__ __align__(16) ushort_t Ks[2][64 * 64];  // linear, XOR-swizzle on read
    __shared__ __align__(16) ushort_t Vt[2][64 * 64];  // d-major, XOR-swizzled
    __shared__ __align__(16) unsigned int Pw[8][32][36];  // per-wave P words
    const int L = blockIdx.x;                          // 0..511
    const int xcd = L & 7;
    const int u = (L & 255) >> 3;                      // 0..31 within half-set
    const int bh = ((u & 7) << 3) | xcd;               // 8 bh share an XCD
    const int qt = (L < 256) ? (7 - (u >> 3)) : (u >> 3);  // heavy first; L/L+256 complementary
    const int b = bh >> 4, h = bh & 15;
    const int t = threadIdx.x, wave = t >> 6, lane = t & 63;
    const int g = lane >> 4, q16 = lane & 15;
    const size_t base = ((size_t)b * NT) * 3072 + h * NHD;
    const ushort_t* qp_base = qkv + base;
    const ushort_t* kb = qkv + base + 1024;
    const ushort_t* vbt = vT + (size_t)bh * 64 * NT;   // rows d, length NT
    const int krw = lane >> 3, kck = lane & 7;
    const int ksrc = (kck ^ krw) * 8;                  // row&7 == krw (row = wave*8+krw)

    bf16x8 ones_f;
    {
        uint4 uu = {0x3F803F80u, 0x3F803F80u, 0x3F803F80u, 0x3F803F80u};
        ones_f = __builtin_bit_cast(bf16x8, uu);
    }

    // 512 threads cover 64 rows x 8 chunks: one issue per thread per buffer.
    auto stageK = [&](int kv, int buf) {
        const int rowbase = wave * 8;                  // wave-uniform
        async_load16(kb + (size_t)(kv * 64 + rowbase + krw) * 3072 + ksrc,
                     &Ks[buf][rowbase * 64]);
    };
    auto stageV = [&](int kv, int buf) {
        const int rowbase = wave * 8;                  // wave-uniform
        const int scol = (kck ^ krw ^ wave) * 8;       // c(d) = krw ^ wave
        async_load16(vbt + (size_t)(rowbase + krw) * NT + kv * 64 + scol,
                     &Vt[buf][rowbase * 64]);
    };

    const int q0 = qt * 256;
    const int wq0 = q0 + wave * 32;
    bf16x8 qf[2][2];
    #pragma unroll
    for (int qb2 = 0; qb2 < 2; qb2++) {
        const ushort_t* qp = qp_base + (size_t)(wq0 + 16 * qb2 + q16) * 3072 + 8 * g;
        qf[qb2][0] = *(const bf16x8*)qp;
        qf[qb2][1] = *(const bf16x8*)(qp + 32);
    }
    f32x4 of[2][4] = {};
    f32x4 of4[2] = {};               // row-sum accumulator (l), via ones-MFMA
    const int nkv = 4 * qt + 4;

    stageK(0, 0);
    stageV(0, 0);
    __syncthreads();                 // drains vmcnt before first use

    for (int kv = 0; kv < nkv; ++kv) {
        const int cur = kv & 1, nxt = cur ^ 1;
        if (kv + 1 < nkv) {
            stageK(kv + 1, nxt);
            stageV(kv + 1, nxt);
        }
        __builtin_amdgcn_sched_barrier(0);   // pin prefetch issue before compute

        const int kbase = kv * 64;
        if (kbase <= wq0 + 31) {
            bf16x8 kf[4][2];
            #pragma unroll
            for (int n = 0; n < 4; n++)
                #pragma unroll
                for (int kd = 0; kd < 2; kd++) {
                    int row = n * 16 + q16;
                    int a = row * 128 + (kd * 64 + 16 * g);
                    a ^= ((row & 7) << 4);
                    kf[n][kd] = *(const bf16x8*)((const char*)&Ks[cur][0] + a);
                }

            f32x4 sf[2][4] = {};
            #pragma unroll
            for (int n = 0; n < 4; n++)
                #pragma unroll
                for (int kd = 0; kd < 2; kd++) {
                    sf[0][n] = __builtin_amdgcn_mfma_f32_16x16x32_bf16(
                        kf[n][kd], qf[0][kd], sf[0][n], 0, 0, 0);
                    sf[1][n] = __builtin_amdgcn_mfma_f32_16x16x32_bf16(
                        kf[n][kd], qf[1][kd], sf[1][n], 0, 0, 0);
                }

            #pragma unroll
            for (int qb2 = 0; qb2 < 2; qb2++) {
                const int wqb = wq0 + 16 * qb2 + q16;
                const bool partial = (kbase + 63 > wq0 + 16 * qb2);
                float p[4][4];
                #pragma unroll
                for (int n = 0; n < 4; n++)
                    #pragma unroll
                    for (int r = 0; r < 4; r++) {
                        float v = sf[qb2][n][r];
                        if (partial) {
                            int kg = kbase + n * 16 + 4 * g + r;
                            if (kg > wqb) v = -1.0e30f;   // exp2 -> 0
                        }
                        p[n][r] = exp2_fast(v);
                    }
                unsigned int* pr = &Pw[wave][16 * qb2 + q16][0];
                #pragma unroll
                for (int n = 0; n < 4; n++) {
                    uint2 wv;
                    wv.x = cvt_pk_bf16(p[n][0], p[n][1]);
                    wv.y = cvt_pk_bf16(p[n][2], p[n][3]);
                    *(uint2*)(pr + 8 * n + 2 * g) = wv;   // 8B-aligned
                }
            }

            #pragma unroll
            for (int kbk = 0; kbk < 2; kbk++) {
                bf16x8 pfr[2];
                #pragma unroll
                for (int qb2 = 0; qb2 < 2; qb2++) {
                    const unsigned int* pr = &Pw[wave][16 * qb2 + q16][0];
                    uint4 pu = *(const uint4*)(pr + 16 * kbk + 4 * g);  // 16B-aligned
                    pfr[qb2] = __builtin_bit_cast(bf16x8, pu);
                }
                of4[0] = __builtin_amdgcn_mfma_f32_16x16x32_bf16(
                    ones_f, pfr[0], of4[0], 0, 0, 0);
                of4[1] = __builtin_amdgcn_mfma_f32_16x16x32_bf16(
                    ones_f, pfr[1], of4[1], 0, 0, 0);
                #pragma unroll
                for (int nf = 0; nf < 4; nf++) {
                    const int d = nf * 16 + q16;
                    int a = (d << 7) + (kbk * 64 + 16 * g);
                    a ^= (((d & 7) ^ ((d >> 3) & 7)) << 4);
                    bf16x8 vf = *(const bf16x8*)((const char*)&Vt[cur][0] + a);
                    of[0][nf] = __builtin_amdgcn_mfma_f32_16x16x32_bf16(
                        vf, pfr[0], of[0][nf], 0, 0, 0);
                    of[1][nf] = __builtin_amdgcn_mfma_f32_16x16x32_bf16(
                        vf, pfr[1], of[1][nf], 0, 0, 0);
                }
            }
        }

        __syncthreads();   // drains K+V prefetch + buffer handoff
    }

    #pragma unroll
    for (int qb2 = 0; qb2 < 2; qb2++) {
        float rl = 1.f / of4[qb2][0];
        const size_t orow = (size_t)b * NT + q0 + wave * 32 + 16 * qb2 + q16;
        #pragma unroll
        for (int nf = 0; nf < 4; nf++) {
            ushort4 o4;
            o4.x = f2bf(of[qb2][nf][0] * rl);
            o4.y = f2bf(of[qb2][nf][1] * rl);
            o4.z = f2bf(of[qb2][nf][2] * rl);
            o4.w = f2bf(of[qb2][nf][3] * rl);
            *(ushort4*)(out + orow * ND + h * NHD + nf * 16 + 4 * g) = o4;
        }
    }
}

// ---------------------------------------------------------------------------
extern "C" void kernel_launch(void* const* d_in, const int* in_sizes, int n_in,
                              void* d_out, int out_size, void* d_ws, size_t ws_size,
                              hipStream_t stream) {
    const float* x     = (const float*)d_in[0];
    const float* ln1_g = (const float*)d_in[1];
    const float* ln1_b = (const float*)d_in[2];
    const float* ln2_g = (const float*)d_in[3];
    const float* ln2_b = (const float*)d_in[4];
    const float* Wq    = (const float*)d_in[5];
    const float* Wk    = (const float*)d_in[6];
    const float* Wv    = (const float*)d_in[7];
    const float* Wo    = (const float*)d_in[8];
    const float* bo    = (const float*)d_in[9];
    const float* W1    = (const float*)d_in[10];
    const float* b1    = (const float*)d_in[11];
    const float* W2    = (const float*)d_in[12];
    const float* b2    = (const float*)d_in[13];
    float* outp = (float*)d_out;

    char* w = (char*)d_ws;
    ushort_t* Wqkv_t = (ushort_t*)(w);                    // 6 MiB  (3072x1024)
    ushort_t* Wo_t   = (ushort_t*)(w + 6291456);          // 2 MiB  (1024x1024)
    ushort_t* W1_t   = (ushort_t*)(w + 8388608);          // 8 MiB  (4096x1024)
    ushort_t* W2_t   = (ushort_t*)(w + 16777216);         // 8 MiB  (1024x4096)
    ushort_t* xn     = (ushort_t*)(w + 25165824);         // 16 MiB (8192x1024), also hn
    ushort_t* qkv    = (ushort_t*)(w + 41943040);         // 48 MiB (8192x3072; V third unused)
    ushort_t* attn_o = qkv + (size_t)MTOK * 3072;         // 16 MiB (8192x1024)
    ushort_t* ff1    = qkv;                               // 64 MiB (8192x4096) reuse
    ushort_t* hbuf   = (ushort_t*)(w + 41943040 + 67108864);      // 16 MiB (bf16)
    ushort_t* vT     = (ushort_t*)(w + 41943040 + 67108864 + 16777216); // 16 MiB (4096x2048)

    dim3 tb(32, 8);
    transpose_qkv_to_bf16<<<dim3(2, 32, 48), tb, 0, stream>>>(Wq, Wk, Wv, Wqkv_t);
    transpose_to_bf16<<<dim3(32, 32), tb, 0, stream>>>(Wo, Wo_t, 1024, 1024);
    transpose_to_bf16<<<dim3(128, 32), tb, 0, stream>>>(W1, W1_t, 1024, 4096);
    transpose_to_bf16<<<dim3(32, 128), tb, 0, stream>>>(W2, W2_t, 4096, 1024);

    layernorm_to_bf16<<<MTOK, 256, 0, stream>>>(x, ln1_g, ln1_b, xn);

    // QKV via gemm2b64 (2 blocks/CU overlap): Q,K row-major; V -> vT transposed
    gemm2b64<false, false, 0, false, 1><<<dim3(24, 64), 256, 0, stream>>>(
        xn, Wqkv_t, nullptr, nullptr, qkv, vT, MTOK, 3072, 1024);

    attn_kernel<<<dim3(512), 512, 0, stream>>>(qkv, vT, attn_o);

    // Wo via gemm2b64: h = attn@Wo + bo + x (bf16 out)
    gemm2b64<true, false, 1, false><<<dim3(8, 64), 256, 0, stream>>>(
        attn_o, Wo_t, bo, x, hbuf, nullptr, MTOK, 1024, 1024);

    layernorm_bf16<<<MTOK, 256, 0, stream>>>(hbuf, ln2_g, ln2_b, xn);

    // FFN1: 256x256 gemm8p
    gemm8p<true, true, 0, false><<<dim3(16, 32), 512, 0, stream>>>(
        xn, W1_t, b1, nullptr, ff1, MTOK, NF, 1024);

    // FFN2: N=1024, K=4096 -> gemm2b64
    gemm2b64<true, false, 2, true><<<dim3(8, 64), 256, 0, stream>>>(
        ff1, W2_t, b2, hbuf, outp, nullptr, MTOK, 1024, NF);
}